// Round 3
// baseline (1358.812 us; speedup 1.0000x reference)
//
#include <hip/hip_runtime.h>
#include <hip/hip_bf16.h>
#include <math.h>

typedef __hip_bfloat16 bf16;

#define N_TOK 1024
#define DIM 2048
#define NHEADS 16
#define KVH 2
#define DH 128
#define GQ 8
#define NWIN 64
#define CMP_BLK 32
#define NCMP 65        // MEM_KV + NWIN
#define NFINE 16
#define SEL_BLK 64
#define T_TOT 320
#define CDIM 4096      // CMP_BLK*DH
#define SCALE 0.08838834764831845f

static __device__ __forceinline__ float b2f(bf16 v){ return __bfloat162float(v); }
static __device__ __forceinline__ float bfbits2f(unsigned int u){
  union { unsigned int i; float f; } x; x.i = u << 16; return x.f;
}

// ---------------- RMSNorm: x fp32 [N,DIM] -> xn fp32 ----------------
__global__ __launch_bounds__(256) void rmsnorm_kernel(const float* __restrict__ x,
                                                      const float* __restrict__ g,
                                                      float* __restrict__ xn){
  int n = blockIdx.x, tid = threadIdx.x;
  __shared__ float red[256];
  const float* row = x + (size_t)n*DIM;
  float vals[8];
  float s = 0.f;
  #pragma unroll
  for (int i = 0; i < 8; ++i){ float v = row[tid + i*256]; vals[i] = v; s += v*v; }
  red[tid] = s; __syncthreads();
  for (int st = 128; st > 0; st >>= 1){ if (tid < st) red[tid] += red[tid+st]; __syncthreads(); }
  float scale = 1.0f / sqrtf(red[0]/(float)DIM + 1e-6f);
  #pragma unroll
  for (int i = 0; i < 8; ++i){
    int c = tid + i*256;
    xn[(size_t)n*DIM + c] = vals[i]*scale*g[c];
  }
}

// ---------------- Split-K GEMM (64x64 tile) — kept for the small shapes (gates, MLP2) --------------
__global__ __launch_bounds__(256) void gemm_splitk_kernel(const void* __restrict__ Av, int a_is_bf16,
                                                          const float* __restrict__ afold,
                                                          const float* __restrict__ B, int ldb,
                                                          float* __restrict__ C,
                                                          int M, int N, int K, int kchunk){
  __shared__ __align__(16) float As[16*68];
  __shared__ __align__(16) float Bs[16*68];
  int tid = threadIdx.x;
  int tx = tid & 15, ty = tid >> 4;
  int m0 = blockIdx.y * 64, n0 = blockIdx.x * 64;
  int kz = blockIdx.z * kchunk;
  const float* Af = (const float*)Av;
  const bf16*  Ab = (const bf16*)Av;
  float c[4][4] = {};
  for (int k0 = kz; k0 < kz + kchunk; k0 += 16){
    #pragma unroll
    for (int i = 0; i < 4; ++i){
      int idx = tid + i*256;
      int kk = idx & 15, m = idx >> 4;
      size_t aidx = (size_t)(m0+m)*K + k0 + kk;
      float av = a_is_bf16 ? b2f(Ab[aidx]) : Af[aidx];
      if (afold) av = fmaxf(av + afold[k0+kk], 0.f);
      As[kk*68 + m] = av;
    }
    #pragma unroll
    for (int i = 0; i < 4; ++i){
      int idx = tid + i*256;
      int nn = idx & 63, kk = idx >> 6;
      int col = n0 + nn;
      Bs[kk*68 + nn] = (col < N) ? B[(size_t)(k0+kk)*ldb + col] : 0.f;
    }
    __syncthreads();
    #pragma unroll
    for (int kk = 0; kk < 16; ++kk){
      float a[4], b[4];
      *(float4*)a = *(const float4*)&As[kk*68 + ty*4];
      *(float4*)b = *(const float4*)&Bs[kk*68 + tx*4];
      #pragma unroll
      for (int i = 0; i < 4; ++i)
        #pragma unroll
        for (int j = 0; j < 4; ++j)
          c[i][j] += a[i]*b[j];
    }
    __syncthreads();
  }
  #pragma unroll
  for (int i = 0; i < 4; ++i){
    int row = m0 + ty*4 + i;
    #pragma unroll
    for (int j = 0; j < 4; ++j){
      int col = n0 + tx*4 + j;
      if (col < N) atomicAdd(&C[(size_t)row*N + col], c[i][j]);
    }
  }
}

// ---------------- Split-K GEMM, 128x128 tile, 8x8 micro, double-buffered, 1 barrier/k-step ----------
// Per-thread K accumulation order identical to the 64x64 kernel for matching kchunk, so split-K
// partial values are bit-identical (selection safety). Loop: write staged regs -> buf[s&1];
// barrier; issue global loads for s+1 (latency hides under compute); compute buf[s&1].
// One barrier suffices: writes of step s+1 target buf^1, and the barrier at s+1 orders them
// against the step-s reads of buf^1... (writes follow compute in program order per wave).
__global__ __launch_bounds__(256) void gemm128_db_kernel(const void* __restrict__ Av, int a_is_bf16,
                                                         const float* __restrict__ B, int ldb,
                                                         float* __restrict__ C,
                                                         int M, int N, int K, int kchunk){
  __shared__ __align__(16) float As[2][16][132];
  __shared__ __align__(16) float Bs[2][16][132];
  int tid = threadIdx.x;
  int tx = tid & 15, ty = tid >> 4;
  int m0 = blockIdx.y * 128, n0 = blockIdx.x * 128;
  int kz = blockIdx.z * kchunk;
  const float* Af = (const float*)Av;
  const bf16*  Ab = (const bf16*)Av;
  const int nsteps = kchunk >> 4;
  float acc[2][2][4][4] = {};

  // staging registers
  float4 ra0, ra1, rb0, rb1;
  int4   rab;
  // A-stage addressing (fp32): r=(idx>>2), kc=(idx&3)*4, idx = tid (+256)
  const int ar  = tid >> 2,  akc = (tid & 3) * 4;
  // A-stage addressing (bf16): r=tid>>1, kc=(tid&1)*8
  const int abr = tid >> 1,  abk = (tid & 1) * 8;
  // B-stage addressing: kk=idx>>5, nc=(idx&31)*4
  const int bkk = tid >> 5,  bnc = (tid & 31) * 4;

  // prologue: load step 0
  {
    int k0 = kz;
    if (a_is_bf16){
      rab = *(const int4*)(Ab + (size_t)(m0 + abr)*K + k0 + abk);
    } else {
      ra0 = *(const float4*)(Af + (size_t)(m0 + ar     )*K + k0 + akc);
      ra1 = *(const float4*)(Af + (size_t)(m0 + ar + 64)*K + k0 + akc);
    }
    rb0 = *(const float4*)(B + (size_t)(k0 + bkk    )*ldb + n0 + bnc);
    rb1 = *(const float4*)(B + (size_t)(k0 + bkk + 8)*ldb + n0 + bnc);
  }

  for (int s = 0; s < nsteps; ++s){
    const int buf = s & 1;
    // ---- commit staged regs to LDS
    if (a_is_bf16){
      unsigned int wv[4] = {(unsigned)rab.x,(unsigned)rab.y,(unsigned)rab.z,(unsigned)rab.w};
      #pragma unroll
      for (int m = 0; m < 4; ++m){
        As[buf][abk + 2*m    ][abr] = bfbits2f(wv[m] & 0xffffu);
        As[buf][abk + 2*m + 1][abr] = bfbits2f(wv[m] >> 16);
      }
    } else {
      As[buf][akc    ][ar]      = ra0.x;
      As[buf][akc + 1][ar]      = ra0.y;
      As[buf][akc + 2][ar]      = ra0.z;
      As[buf][akc + 3][ar]      = ra0.w;
      As[buf][akc    ][ar + 64] = ra1.x;
      As[buf][akc + 1][ar + 64] = ra1.y;
      As[buf][akc + 2][ar + 64] = ra1.z;
      As[buf][akc + 3][ar + 64] = ra1.w;
    }
    *(float4*)&Bs[buf][bkk    ][bnc] = rb0;
    *(float4*)&Bs[buf][bkk + 8][bnc] = rb1;
    __syncthreads();
    // ---- issue next-step global loads (consumed at next commit -> latency hidden by compute)
    if (s + 1 < nsteps){
      int k0 = kz + (s+1)*16;
      if (a_is_bf16){
        rab = *(const int4*)(Ab + (size_t)(m0 + abr)*K + k0 + abk);
      } else {
        ra0 = *(const float4*)(Af + (size_t)(m0 + ar     )*K + k0 + akc);
        ra1 = *(const float4*)(Af + (size_t)(m0 + ar + 64)*K + k0 + akc);
      }
      rb0 = *(const float4*)(B + (size_t)(k0 + bkk    )*ldb + n0 + bnc);
      rb1 = *(const float4*)(B + (size_t)(k0 + bkk + 8)*ldb + n0 + bnc);
    }
    // ---- compute on current buffer
    #pragma unroll
    for (int kk = 0; kk < 16; ++kk){
      float4 a0 = *(const float4*)&As[buf][kk][ty*4];
      float4 a1 = *(const float4*)&As[buf][kk][64 + ty*4];
      float4 b0 = *(const float4*)&Bs[buf][kk][tx*4];
      float4 b1 = *(const float4*)&Bs[buf][kk][64 + tx*4];
      float ar2[2][4] = {{a0.x,a0.y,a0.z,a0.w},{a1.x,a1.y,a1.z,a1.w}};
      float br2[2][4] = {{b0.x,b0.y,b0.z,b0.w},{b1.x,b1.y,b1.z,b1.w}};
      #pragma unroll
      for (int hi = 0; hi < 2; ++hi)
        #pragma unroll
        for (int i = 0; i < 4; ++i)
          #pragma unroll
          for (int hj = 0; hj < 2; ++hj)
            #pragma unroll
            for (int j = 0; j < 4; ++j)
              acc[hi][hj][i][j] += ar2[hi][i] * br2[hj][j];
    }
  }
  #pragma unroll
  for (int hi = 0; hi < 2; ++hi)
    #pragma unroll
    for (int i = 0; i < 4; ++i){
      int row = m0 + hi*64 + ty*4 + i;
      #pragma unroll
      for (int hj = 0; hj < 2; ++hj)
        #pragma unroll
        for (int j = 0; j < 4; ++j){
          int col = n0 + hj*64 + tx*4 + j;
          atomicAdd(&C[(size_t)row*N + col], acc[hi][hj][i][j]);
        }
    }
}

// ---------------- Split-K GEMM, 64x128 tile, 8x4 micro, double-buffered (fp32 A only) ---------------
// For small-M shapes (kv: M=1024 N=512; MLP1: M=128 N=4096) where 128x128 gives too few WGs.
// Same per-thread K order as the other GEMM kernels -> bit-identical split-K partials.
__global__ __launch_bounds__(256) void gemm64_db_kernel(const float* __restrict__ A,
                                                        const float* __restrict__ B, int ldb,
                                                        float* __restrict__ C,
                                                        int M, int N, int K, int kchunk){
  __shared__ __align__(16) float As[2][16][68];
  __shared__ __align__(16) float Bs[2][16][132];
  int tid = threadIdx.x;
  int tx = tid & 31, ty = tid >> 5;          // cols tx*4 (0..127), row groups ty*4 & 32+ty*4
  int m0 = blockIdx.y * 64, n0 = blockIdx.x * 128;
  int kz = blockIdx.z * kchunk;
  const int nsteps = kchunk >> 4;
  float acc[2][4][4] = {};

  float4 ra, rb0, rb1;
  const int ar  = tid >> 2,  akc = (tid & 3) * 4;   // 64x16: one float4/thread
  const int bkk = tid >> 5,  bnc = (tid & 31) * 4;

  {
    int k0 = kz;
    ra  = *(const float4*)(A + (size_t)(m0 + ar)*K + k0 + akc);
    rb0 = *(const float4*)(B + (size_t)(k0 + bkk    )*ldb + n0 + bnc);
    rb1 = *(const float4*)(B + (size_t)(k0 + bkk + 8)*ldb + n0 + bnc);
  }

  for (int s = 0; s < nsteps; ++s){
    const int buf = s & 1;
    As[buf][akc    ][ar] = ra.x;
    As[buf][akc + 1][ar] = ra.y;
    As[buf][akc + 2][ar] = ra.z;
    As[buf][akc + 3][ar] = ra.w;
    *(float4*)&Bs[buf][bkk    ][bnc] = rb0;
    *(float4*)&Bs[buf][bkk + 8][bnc] = rb1;
    __syncthreads();
    if (s + 1 < nsteps){
      int k0 = kz + (s+1)*16;
      ra  = *(const float4*)(A + (size_t)(m0 + ar)*K + k0 + akc);
      rb0 = *(const float4*)(B + (size_t)(k0 + bkk    )*ldb + n0 + bnc);
      rb1 = *(const float4*)(B + (size_t)(k0 + bkk + 8)*ldb + n0 + bnc);
    }
    #pragma unroll
    for (int kk = 0; kk < 16; ++kk){
      float4 a0 = *(const float4*)&As[buf][kk][ty*4];
      float4 a1 = *(const float4*)&As[buf][kk][32 + ty*4];
      float4 b  = *(const float4*)&Bs[buf][kk][tx*4];
      float ar2[2][4] = {{a0.x,a0.y,a0.z,a0.w},{a1.x,a1.y,a1.z,a1.w}};
      float br2[4]    = {b.x,b.y,b.z,b.w};
      #pragma unroll
      for (int q = 0; q < 2; ++q)
        #pragma unroll
        for (int i = 0; i < 4; ++i)
          #pragma unroll
          for (int j = 0; j < 4; ++j)
            acc[q][i][j] += ar2[q][i] * br2[j];
    }
  }
  #pragma unroll
  for (int q = 0; q < 2; ++q)
    #pragma unroll
    for (int i = 0; i < 4; ++i){
      int row = m0 + q*32 + ty*4 + i;
      #pragma unroll
      for (int j = 0; j < 4; ++j){
        int col = n0 + tx*4 + j;
        atomicAdd(&C[(size_t)row*N + col], acc[q][i][j]);
      }
    }
}

// ---------------- RoPE: q fp32 [n][2048], kv fp32 [n][512] -> qr bf16 [n][2048], kr bf16 [n][256] ----
__global__ __launch_bounds__(256) void rope_kernel(const float* __restrict__ q,
    const float* __restrict__ kv, bf16* __restrict__ qr, bf16* __restrict__ kr){
  int n = blockIdx.x, tid = threadIdx.x;
  const float* qrow = q + (size_t)n*DIM;
  bf16* qrrow = qr + (size_t)n*DIM;
  #pragma unroll
  for (int i = 0; i < 4; ++i){
    int p = tid + i*256;
    int hd = p >> 6, ii = p & 63;
    float inv = powf(10000.f, -(float)ii/64.f);
    float ang = (float)n * inv;
    float cs = cosf(ang), sn = sinf(ang);
    float x1 = qrow[hd*DH + 2*ii], x2 = qrow[hd*DH + 2*ii + 1];
    qrrow[hd*DH + 2*ii]     = __float2bfloat16(x1*cs - x2*sn);
    qrrow[hd*DH + 2*ii + 1] = __float2bfloat16(x1*sn + x2*cs);
  }
  if (tid < 128){
    int h = tid >> 6, ii = tid & 63;
    float inv = powf(10000.f, -(float)ii/64.f);
    float ang = (float)n * inv;
    float cs = cosf(ang), sn = sinf(ang);
    const float* kvrow = kv + (size_t)n*512;
    float x1 = kvrow[h*DH + 2*ii], x2 = kvrow[h*DH + 2*ii + 1];
    bf16* krrow = kr + (size_t)n*256;
    krrow[h*DH + 2*ii]     = __float2bfloat16(x1*cs - x2*sn);
    krrow[h*DH + 2*ii + 1] = __float2bfloat16(x1*sn + x2*cs);
  }
}

// ---------------- Build compression-MLP input f [128][CDIM] (k: voff=0, v: voff=256) ----------------
__global__ __launch_bounds__(256) void build_f_kernel(const float* __restrict__ kv, int voff,
    const float* __restrict__ pos, float* __restrict__ f){
  int bw = blockIdx.x;           // h*NWIN + w
  int h = bw >> 6, w = bw & 63;
  int tid = threadIdx.x;
  for (int idx = tid; idx < CMP_BLK*DH; idx += 256){
    int j = idx >> 7, d = idx & 127;
    int t = w*16 + j - 16;       // padded window index
    float kvv = (t >= 0) ? kv[(size_t)t*512 + voff + h*DH + d] : 0.f;
    f[(size_t)bw*CDIM + idx] = kvv + pos[(h*CMP_BLK + j)*DH + d];
  }
}

// ---------------- Assemble ck/cv [KVH][NCMP][DH]; MLP second bias folded here ----------------
__global__ __launch_bounds__(256) void assemble_kernel(const float* __restrict__ ckb,
    const float* __restrict__ cvb, const float* __restrict__ mem_kv,
    const float* __restrict__ bk2, const float* __restrict__ bv2,
    float* __restrict__ ck, float* __restrict__ cv){
  int j = blockIdx.x;            // 0..64
  int tid = threadIdx.x;         // 256 = KVH*DH
  int h = tid >> 7, d = tid & 127;
  float kvx, vvx;
  if (j == 0){
    kvx = mem_kv[(0*KVH + h)*DH + d];
    vvx = mem_kv[(1*KVH + h)*DH + d];
  } else {
    kvx = ckb[((size_t)h*NWIN + (j-1))*DH + d] + bk2[d];
    vvx = cvb[((size_t)h*NWIN + (j-1))*DH + d] + bv2[d];
  }
  ck[((size_t)h*NCMP + j)*DH + d] = kvx;
  cv[((size_t)h*NCMP + j)*DH + d] = vvx;
}

// ---------------- Compressed attention (pre-rope q, fp32) + importance + top-4 selection ----------------
__global__ __launch_bounds__(256) void cmp_attn_kernel(const float* __restrict__ q,
    const float* __restrict__ ck, const float* __restrict__ cv,
    bf16* __restrict__ cmp_o, int* __restrict__ sel){
  int bx = blockIdx.x;
  int h = bx >> 10, n = bx & 1023;
  int tid = threadIdx.x;
  __shared__ float cks[NCMP*129];
  __shared__ float qs[GQ*DH];
  __shared__ float sims[GQ*66];
  __shared__ float red[GQ*32];
  __shared__ float impb[NFINE];
  for (int idx = tid; idx < NCMP*DH; idx += 256){
    int j = idx >> 7, d = idx & 127;
    cks[j*129 + d] = ck[((size_t)h*NCMP + j)*DH + d];
  }
  for (int idx = tid; idx < GQ*DH; idx += 256)
    qs[idx] = q[(size_t)n*DIM + h*(GQ*DH) + idx];
  __syncthreads();
  for (int p = tid; p < GQ*NCMP; p += 256){
    int g = p / NCMP, j = p % NCMP;
    float acc = 0.f;
    const float* qp = &qs[g*DH];
    const float* kp = &cks[j*129];
    #pragma unroll 4
    for (int d = 0; d < DH; ++d) acc += qp[d]*kp[d];
    sims[g*66 + j] = acc * SCALE;
  }
  __syncthreads();
  if (tid < NFINE){
    float s = 0.f;
    for (int g = 0; g < GQ; ++g)
      #pragma unroll
      for (int c = 0; c < 4; ++c)
        s += sims[g*66 + 1 + tid*4 + c];
    impb[tid] = s;
  }
  __syncthreads();
  if (tid == 0){
    int own = n >> 6;
    impb[own] = -1e30f;
    int selbuf[5];
    #pragma unroll
    for (int r = 0; r < 4; ++r){
      float best = -1e38f; int bi = 0;
      for (int f = 0; f < NFINE; ++f)
        if (impb[f] > best){ best = impb[f]; bi = f; }   // strict > : lowest index on ties
      selbuf[r] = bi; impb[bi] = -1e38f;
    }
    selbuf[4] = own;
    for (int r = 0; r < 5; ++r) sel[(size_t)(h*N_TOK + n)*8 + r] = selbuf[r];
  }
  int g = tid >> 5, lane = tid & 31;
  float m = -1e38f;
  for (int j = lane; j < NCMP; j += 32) m = fmaxf(m, sims[g*66 + j]);
  red[g*32 + lane] = m; __syncthreads();
  for (int st = 16; st > 0; st >>= 1){ if (lane < st) red[g*32+lane] = fmaxf(red[g*32+lane], red[g*32+lane+st]); __syncthreads(); }
  float gm = red[g*32]; __syncthreads();
  float ps = 0.f;
  for (int j = lane; j < NCMP; j += 32){ float e = expf(sims[g*66+j] - gm); sims[g*66+j] = e; ps += e; }
  red[g*32+lane] = ps; __syncthreads();
  for (int st = 16; st > 0; st >>= 1){ if (lane < st) red[g*32+lane] += red[g*32+lane+st]; __syncthreads(); }
  float inv = 1.f / red[g*32]; __syncthreads();
  for (int j = lane; j < NCMP; j += 32) sims[g*66+j] *= inv;
  __syncthreads();
  for (int p = tid; p < GQ*DH; p += 256){
    int gg = p >> 7, d = p & 127;
    float acc = 0.f;
    const float* cvp = cv + (size_t)h*NCMP*DH + d;
    for (int j = 0; j < NCMP; ++j) acc += sims[gg*66 + j] * cvp[j*DH];
    cmp_o[(size_t)n*DIM + (h*GQ + gg)*DH + d] = __float2bfloat16(acc);
  }
}

// ---------------- Fine (selected-block) attention: roped q/k (bf16), raw v (fp32 strided) ------------
__global__ __launch_bounds__(256) void fine_attn_kernel(const bf16* __restrict__ qr,
    const bf16* __restrict__ kr, const float* __restrict__ kv,
    const int* __restrict__ sel, bf16* __restrict__ fine_o){
  int bx = blockIdx.x;
  int h = bx >> 10, n = bx & 1023;
  int tid = threadIdx.x;
  __shared__ float kt[SEL_BLK*129];
  __shared__ float qs[GQ*DH];
  __shared__ float sims[GQ*321];
  __shared__ float red[GQ*32];
  int sel5[5];
  #pragma unroll
  for (int r = 0; r < 5; ++r){
    int b = sel[(size_t)(h*N_TOK + n)*8 + r];
    sel5[r] = (b < 0) ? 0 : (b > 15 ? 15 : b);
  }
  for (int idx = tid; idx < GQ*DH; idx += 256)
    qs[idx] = b2f(qr[(size_t)n*DIM + h*(GQ*DH) + idx]);
  for (int tile = 0; tile < 5; ++tile){
    int blk = sel5[tile];
    __syncthreads();
    for (int idx = tid; idx < SEL_BLK*DH; idx += 256){
      int tl = idx >> 7, d = idx & 127;
      kt[tl*129 + d] = b2f(kr[(size_t)(blk*SEL_BLK + tl)*256 + h*DH + d]);
    }
    __syncthreads();
    for (int p = tid; p < GQ*SEL_BLK; p += 256){
      int g = p >> 6, t = p & 63;
      float acc = 0.f;
      const float* qp = &qs[g*DH];
      const float* kp = &kt[t*129];
      #pragma unroll 4
      for (int d = 0; d < DH; ++d) acc += qp[d]*kp[d];
      sims[g*321 + tile*SEL_BLK + t] = acc * SCALE;
    }
  }
  __syncthreads();
  int g = tid >> 5, lane = tid & 31;
  float m = -1e38f;
  for (int t = lane; t < T_TOT; t += 32) m = fmaxf(m, sims[g*321 + t]);
  red[g*32+lane] = m; __syncthreads();
  for (int st = 16; st > 0; st >>= 1){ if (lane < st) red[g*32+lane] = fmaxf(red[g*32+lane], red[g*32+lane+st]); __syncthreads(); }
  float gm = red[g*32]; __syncthreads();
  float ps = 0.f;
  for (int t = lane; t < T_TOT; t += 32){ float e = expf(sims[g*321+t] - gm); sims[g*321+t] = e; ps += e; }
  red[g*32+lane] = ps; __syncthreads();
  for (int st = 16; st > 0; st >>= 1){ if (lane < st) red[g*32+lane] += red[g*32+lane+st]; __syncthreads(); }
  float inv = 1.f / red[g*32]; __syncthreads();
  for (int t = lane; t < T_TOT; t += 32) sims[g*321+t] *= inv;
  float acc[4] = {0.f,0.f,0.f,0.f};
  for (int tile = 0; tile < 5; ++tile){
    int blk = sel5[tile];
    __syncthreads();
    for (int idx = tid; idx < SEL_BLK*DH; idx += 256){
      int tl = idx >> 7, d = idx & 127;
      kt[tl*129 + d] = kv[(size_t)(blk*SEL_BLK + tl)*512 + 256 + h*DH + d];
    }
    __syncthreads();
    #pragma unroll
    for (int i = 0; i < 4; ++i){
      int p = tid + i*256;
      int gg = p >> 7, d = p & 127;
      float a = acc[i];
      const float* sp = &sims[gg*321 + tile*SEL_BLK];
      const float* vp = &kt[d];
      for (int t = 0; t < SEL_BLK; ++t) a += sp[t]*vp[t*129];
      acc[i] = a;
    }
  }
  #pragma unroll
  for (int i = 0; i < 4; ++i){
    int p = tid + i*256;
    int gg = p >> 7, d = p & 127;
    fine_o[(size_t)n*DIM + (h*GQ + gg)*DH + d] = __float2bfloat16(acc[i]);
  }
}

// ---------------- Sliding-window attention, flash-style online softmax --------------------------
// Register-blocked outer-product structure (see round-0 notes). Math identical to scalar version.
__global__ __launch_bounds__(256) void slide_attn_kernel(const bf16* __restrict__ qr,
    const bf16* __restrict__ kr, const float* __restrict__ kv,
    bf16* __restrict__ slide_o){
  int hq = blockIdx.y;          // 16 heads
  int qt = blockIdx.x;          // 32 query tiles of 32
  int h = hq >> 3;
  int n0 = qt * 32;
  int tid = threadIdx.x;
  __shared__ float qT[128*36];   // [d][qi], pad 36  (18.0 KB)
  __shared__ float kvb[128*68];  // K^T [d][t] pad 68 (QK) | V [t][128] (PV)  (34.0 KB)
  __shared__ float stT[64*36];   // [t][qi] exp'd probs, pad 36 (9.0 KB)

  const int ty  = tid >> 5;     // 0..7  : row group (4 queries)
  const int tx  = tid & 31;     // 0..31
  const int qi0 = ty << 2;

  for (int c = tid; c < 512; c += 256){
    int qi = c & 31, d0 = (c >> 5) << 3;
    int4 w = *(const int4*)(qr + (size_t)(n0+qi)*DIM + hq*DH + d0);
    float* dst = &qT[(size_t)d0*36 + qi];
    unsigned int wv[4] = {(unsigned)w.x,(unsigned)w.y,(unsigned)w.z,(unsigned)w.w};
    #pragma unroll
    for (int m = 0; m < 4; ++m){
      dst[(2*m  )*36] = bfbits2f(wv[m] & 0xffffu);
      dst[(2*m+1)*36] = bfbits2f(wv[m] >> 16);
    }
  }

  float acc[4][4] = {};
  float mrow[4] = {-1e30f,-1e30f,-1e30f,-1e30f};
  float lrow[4] = {0.f,0.f,0.f,0.f};
  float arow[4];
  const int kstart = n0 - 128;

  for (int tile = 0; tile < 5; ++tile){
    const int kbase = kstart + tile*64;
    __syncthreads();
    for (int c = tid; c < 1024; c += 256){
      int t = c & 63, d0 = (c >> 6) << 3;
      int kg = kbase + t;
      int kgc = min(max(kg, 0), N_TOK-1);          // clamp; garbage is masked later
      int4 w = *(const int4*)(kr + (size_t)kgc*256 + h*DH + d0);
      float* dst = &kvb[(size_t)d0*68 + t];
      unsigned int wv[4] = {(unsigned)w.x,(unsigned)w.y,(unsigned)w.z,(unsigned)w.w};
      #pragma unroll
      for (int m = 0; m < 4; ++m){
        dst[(2*m  )*68] = bfbits2f(wv[m] & 0xffffu);
        dst[(2*m+1)*68] = bfbits2f(wv[m] >> 16);
      }
    }
    __syncthreads();
    float c0[8] = {};
    {
      const float* aP = qT + qi0;
      const float* bP = kvb + (tx << 1);
      #pragma unroll 4
      for (int d = 0; d < 128; ++d){
        float4 a = *(const float4*)(aP + d*36);
        float2 b = *(const float2*)(bP + d*68);
        c0[0] += a.x*b.x; c0[1] += a.x*b.y;
        c0[2] += a.y*b.x; c0[3] += a.y*b.y;
        c0[4] += a.z*b.x; c0[5] += a.z*b.y;
        c0[6] += a.w*b.x; c0[7] += a.w*b.y;
      }
    }
    const int kg0 = kbase + (tx << 1);
    #pragma unroll
    for (int i = 0; i < 4; ++i){
      int qg = n0 + qi0 + i;
      int d0 = qg - kg0, d1 = d0 - 1;
      bool v0 = (kg0   >= 0) && (kg0   < N_TOK) && (d0 <= 128) && (d0 >= -128);
      bool v1 = (kg0+1 >= 0) && (kg0+1 < N_TOK) && (d1 <= 128) && (d1 >= -128);
      float s0 = v0 ? c0[i*2  ]*SCALE : -1e30f;
      float s1 = v1 ? c0[i*2+1]*SCALE : -1e30f;
      float mi = fmaxf(s0, s1);
      #pragma unroll
      for (int off = 1; off < 32; off <<= 1) mi = fmaxf(mi, __shfl_xor(mi, off));
      float mold = mrow[i];
      float mnew = fmaxf(fmaxf(mold, mi), -1e20f);
      arow[i] = expf(mold - mnew);
      mrow[i] = mnew;
      float e0 = expf(s0 - mnew);
      float e1 = expf(s1 - mnew);
      float ps = e0 + e1;
      #pragma unroll
      for (int off = 1; off < 32; off <<= 1) ps += __shfl_xor(ps, off);
      lrow[i] = lrow[i]*arow[i] + ps;
      stT[(size_t)(2*tx  )*36 + qi0 + i] = e0;
      stT[(size_t)(2*tx+1)*36 + qi0 + i] = e1;
    }
    __syncthreads();
    for (int c = tid; c < 2048; c += 256){
      int t = c >> 5, d0 = (c & 31) << 2;
      int kg = kbase + t;
      int kgc = min(max(kg, 0), N_TOK-1);
      float4 v = *(const float4*)(kv + (size_t)kgc*512 + 256 + h*DH + d0);
      *(float4*)&kvb[(size_t)t*128 + d0] = v;
    }
    __syncthreads();
    #pragma unroll
    for (int i = 0; i < 4; ++i){
      float ar = arow[i];
      acc[i][0] *= ar; acc[i][1] *= ar; acc[i][2] *= ar; acc[i][3] *= ar;
    }
    {
      const float* pP = stT + qi0;
      const float* vP = kvb + (tx << 2);
      #pragma unroll 4
      for (int t = 0; t < 64; ++t){
        float4 p = *(const float4*)(pP + t*36);
        float4 v = *(const float4*)(vP + t*128);
        acc[0][0] += p.x*v.x; acc[0][1] += p.x*v.y; acc[0][2] += p.x*v.z; acc[0][3] += p.x*v.w;
        acc[1][0] += p.y*v.x; acc[1][1] += p.y*v.y; acc[1][2] += p.y*v.z; acc[1][3] += p.y*v.w;
        acc[2][0] += p.z*v.x; acc[2][1] += p.z*v.y; acc[2][2] += p.z*v.z; acc[2][3] += p.z*v.w;
        acc[3][0] += p.w*v.x; acc[3][1] += p.w*v.y; acc[3][2] += p.w*v.z; acc[3][3] += p.w*v.w;
      }
    }
  }
  #pragma unroll
  for (int i = 0; i < 4; ++i){
    int row = n0 + qi0 + i;
    float inv = 1.f / lrow[i];
    bf16 o[4];
    o[0] = __float2bfloat16(acc[i][0]*inv);
    o[1] = __float2bfloat16(acc[i][1]*inv);
    o[2] = __float2bfloat16(acc[i][2]*inv);
    o[3] = __float2bfloat16(acc[i][3]*inv);
    *(ushort4*)(slide_o + (size_t)row*DIM + hq*DH + (tx << 2)) = *(const ushort4*)o;
  }
}

// ---------------- Gated combine; gate bias+sigmoid folded here -> ocomb bf16 [n][2048] --------------
__global__ __launch_bounds__(256) void combine_kernel(const bf16* __restrict__ cmp_o,
    const bf16* __restrict__ fine_o, const bf16* __restrict__ slide_o,
    const float* __restrict__ graw, const float* __restrict__ bg,
    bf16* __restrict__ ocomb){
  int n = blockIdx.x, tid = threadIdx.x;
  #pragma unroll
  for (int i = 0; i < 8; ++i){
    int c = tid + i*256;
    int hq = c >> 7;
    float g0 = 1.f/(1.f + expf(-(graw[(size_t)n*48 + hq*3 + 0] + bg[hq*3 + 0])));
    float g1 = 1.f/(1.f + expf(-(graw[(size_t)n*48 + hq*3 + 1] + bg[hq*3 + 1])));
    float g2 = 1.f/(1.f + expf(-(graw[(size_t)n*48 + hq*3 + 2] + bg[hq*3 + 2])));
    size_t idx = (size_t)n*DIM + c;
    ocomb[idx] = __float2bfloat16(b2f(cmp_o[idx])*g0 + b2f(fine_o[idx])*g1 + b2f(slide_o[idx])*g2);
  }
}

extern "C" void kernel_launch(void* const* d_in, const int* in_sizes, int n_in,
                              void* d_out, int out_size, void* d_ws, size_t ws_size,
                              hipStream_t stream)
{
  const float* x      = (const float*)d_in[0];
  const float* g_norm = (const float*)d_in[1];
  const float* W_qkv  = (const float*)d_in[2];
  const float* k_pos  = (const float*)d_in[3];
  const float* v_pos  = (const float*)d_in[4];
  const float* mem_kv = (const float*)d_in[5];
  const float* Wk1    = (const float*)d_in[6];
  const float* bk1    = (const float*)d_in[7];
  const float* Wk2    = (const float*)d_in[8];
  const float* bk2    = (const float*)d_in[9];
  const float* Wv1    = (const float*)d_in[10];
  const float* bv1    = (const float*)d_in[11];
  const float* Wv2    = (const float*)d_in[12];
  const float* bv2    = (const float*)d_in[13];
  const float* Wg     = (const float*)d_in[14];
  const float* bg     = (const float*)d_in[15];
  const float* W_out  = (const float*)d_in[16];
  float* out = (float*)d_out;
  (void)ws_size; (void)in_sizes; (void)n_in; (void)out_size;

  // ---- Workspace layout (bytes), total ~23.6 MB, aggressive region reuse ----
  char* base = (char*)d_ws;
  float* q     = (float*)(base + 0);                 // 8 MB [n][2048] fp32, live -> cmp_attn
  float* xn    = (float*)(base + 8388608);           // 8 MB fp32, live -> kv GEMM
  bf16*  qr    = (bf16*) (base + 8388608);           // 4 MB (over xn, after xn dead)
  bf16*  kr    = (bf16*) (base + 12582912);          // 0.5 MB
  bf16*  ocomb = (bf16*) (base + 8388608);           // 4 MB (over qr, after slide)
  float* kv    = (float*)(base + 16777216);          // 2 MB [n][512] fp32
  float* fbuf  = (float*)(base + 18874368);          // 2 MB fk / fv
  float* hbuf  = (float*)(base + 20971520);          // 2 MB hk / hv (raw, bias folded downstream)
  bf16*  cmp_o = (bf16*) (base + 18874368);          // 4 MB (over fbuf+hbuf, after MLPs)
  float* ckb   = (float*)(base + 23068672);          // 64 KB (raw)
  float* cvb   = (float*)(base + 23134208);          // 64 KB (raw)
  float* ck    = (float*)(base + 23199744);          // 65 KB
  float* cv    = (float*)(base + 23266304);          // 65 KB
  float* gates = (float*)(base + 23332864);          // 192 KB (raw, sigmoid folded in combine)
  int*   sel   = (int*)  (base + 23529472);          // 64 KB   (end: 23,595,008 B)
  bf16*  fine_o  = (bf16*)(base + 0);                // 4 MB (over q, after cmp_attn)
  bf16*  slide_o = (bf16*)(base + 4194304);          // 4 MB (over q upper half)

  // Zero split-K accumulation targets (stream-ordered; graph-capture legal)
  hipMemsetAsync(q,     0, (size_t)N_TOK*DIM*4,  stream);
  hipMemsetAsync(kv,    0, (size_t)N_TOK*512*4,  stream);
  hipMemsetAsync(gates, 0, (size_t)N_TOK*48*4,   stream);
  hipMemsetAsync(ckb,   0, (size_t)KVH*NWIN*DH*4, stream);
  hipMemsetAsync(cvb,   0, (size_t)KVH*NWIN*DH*4, stream);
  hipMemsetAsync(out,   0, (size_t)N_TOK*DIM*4,  stream);

  rmsnorm_kernel<<<N_TOK, 256, 0, stream>>>(x, g_norm, xn);
  // gates_raw = xn @ Wg            [1024 x 48],  small -> old 64x64 kernel
  gemm_splitk_kernel<<<dim3(1, 16, 8), 256, 0, stream>>>(xn, 0, nullptr, Wg, 48, gates, N_TOK, 48, DIM, 256);
  // q = xn @ W_qkv[:, 0:2048]      [1024 x 2048], 128x128 dbuf, kchunk=512 (values match old)
  gemm128_db_kernel<<<dim3(16, 8, 4), 256, 0, stream>>>(xn, 0, W_qkv, 2560, q, N_TOK, 2048, DIM, 512);
  // kv = xn @ W_qkv[:, 2048:2560]  [1024 x 512], 64x128 dbuf, kchunk=256 (values match old)
  gemm64_db_kernel<<<dim3(4, 16, 8), 256, 0, stream>>>(xn, W_qkv + 2048, 2560, kv, N_TOK, 512, DIM, 256);
  // qr, kr (bf16) — xn now dead
  rope_kernel<<<N_TOK, 256, 0, stream>>>(q, kv, qr, kr);
  // compression MLPs (fp32, selection-critical via ck). relu(.+bk1) folded into MLP2 A-load; bk2 into assemble.
  build_f_kernel<<<KVH*NWIN, 256, 0, stream>>>(kv, 0, k_pos, fbuf);
  hipMemsetAsync(hbuf, 0, (size_t)KVH*NWIN*CDIM*4, stream);
  gemm64_db_kernel<<<dim3(32, 2, 8), 256, 0, stream>>>(fbuf, Wk1, CDIM, hbuf, KVH*NWIN, CDIM, CDIM, 512);
  gemm_splitk_kernel<<<dim3(2, 2, 32),  256, 0, stream>>>(hbuf, 0, bk1,     Wk2, DH,   ckb,  KVH*NWIN, DH,   CDIM, 128);
  build_f_kernel<<<KVH*NWIN, 256, 0, stream>>>(kv, 256, v_pos, fbuf);
  hipMemsetAsync(hbuf, 0, (size_t)KVH*NWIN*CDIM*4, stream);
  gemm64_db_kernel<<<dim3(32, 2, 8), 256, 0, stream>>>(fbuf, Wv1, CDIM, hbuf, KVH*NWIN, CDIM, CDIM, 512);
  gemm_splitk_kernel<<<dim3(2, 2, 32),  256, 0, stream>>>(hbuf, 0, bv1,     Wv2, DH,   cvb,  KVH*NWIN, DH,   CDIM, 128);
  assemble_kernel<<<NCMP, 256, 0, stream>>>(ckb, cvb, mem_kv, bk2, bv2, ck, cv);
  // compressed attention + selection (fbuf/hbuf dead -> cmp_o)
  cmp_attn_kernel<<<KVH*N_TOK, 256, 0, stream>>>(q, ck, cv, cmp_o, sel);
  // fine attention (q dead -> fine_o over q region)
  fine_attn_kernel<<<KVH*N_TOK, 256, 0, stream>>>(qr, kr, kv, sel, fine_o);
  // sliding attention (-> slide_o over q upper half)
  slide_attn_kernel<<<dim3(32, 16), 256, 0, stream>>>(qr, kr, kv, slide_o);
  // combine (qr dead -> ocomb over qr); sigmoid(graw+bg) folded here
  combine_kernel<<<N_TOK, 256, 0, stream>>>(cmp_o, fine_o, slide_o, gates, bg, ocomb);
  // out += ocomb @ W_out  (bf16 A, fp32 atomics). NOT selection-critical: z=8 for 4 WG/CU
  // (split-K partial regrouping perturbs out by ~1e-7 << 3.9e-3 absmax — accepted).
  gemm128_db_kernel<<<dim3(16, 8, 8), 256, 0, stream>>>(ocomb, 1, W_out, DIM, out, N_TOK, DIM, DIM, 256);
}

// Round 4
// 1158.165 us; speedup vs baseline: 1.1732x; 1.1732x over previous
//
#include <hip/hip_runtime.h>
#include <hip/hip_bf16.h>
#include <math.h>

typedef __hip_bfloat16 bf16;
typedef __attribute__((ext_vector_type(8))) short bf16x8;
typedef __attribute__((ext_vector_type(4))) float f32x4;

#define N_TOK 1024
#define DIM 2048
#define NHEADS 16
#define KVH 2
#define DH 128
#define GQ 8
#define NWIN 64
#define CMP_BLK 32
#define NCMP 65        // MEM_KV + NWIN
#define NFINE 16
#define SEL_BLK 64
#define T_TOT 320
#define CDIM 4096      // CMP_BLK*DH
#define SCALE 0.08838834764831845f

static __device__ __forceinline__ float b2f(bf16 v){ return __bfloat162float(v); }
static __device__ __forceinline__ float bfbits2f(unsigned int u){
  union { unsigned int i; float f; } x; x.i = u << 16; return x.f;
}
// RNE float->bf16 bits (matches __float2bfloat16 for normal values)
static __device__ __forceinline__ unsigned short f2bf(float f){
  union { float f; unsigned u; } x; x.f = f;
  unsigned r = x.u + 0x7fffu + ((x.u >> 16) & 1u);
  return (unsigned short)(r >> 16);
}

// ---------------- RMSNorm: x fp32 [N,DIM] -> xn fp32 ----------------
__global__ __launch_bounds__(256) void rmsnorm_kernel(const float* __restrict__ x,
                                                      const float* __restrict__ g,
                                                      float* __restrict__ xn){
  int n = blockIdx.x, tid = threadIdx.x;
  __shared__ float red[256];
  const float* row = x + (size_t)n*DIM;
  float vals[8];
  float s = 0.f;
  #pragma unroll
  for (int i = 0; i < 8; ++i){ float v = row[tid + i*256]; vals[i] = v; s += v*v; }
  red[tid] = s; __syncthreads();
  for (int st = 128; st > 0; st >>= 1){ if (tid < st) red[tid] += red[tid+st]; __syncthreads(); }
  float scale = 1.0f / sqrtf(red[0]/(float)DIM + 1e-6f);
  #pragma unroll
  for (int i = 0; i < 8; ++i){
    int c = tid + i*256;
    xn[(size_t)n*DIM + c] = vals[i]*scale*g[c];
  }
}

// ---------------- Split-K GEMM (64x64 tile) — kept for the small shapes (gates, MLP2) --------------
__global__ __launch_bounds__(256) void gemm_splitk_kernel(const void* __restrict__ Av, int a_is_bf16,
                                                          const float* __restrict__ afold,
                                                          const float* __restrict__ B, int ldb,
                                                          float* __restrict__ C,
                                                          int M, int N, int K, int kchunk){
  __shared__ __align__(16) float As[16*68];
  __shared__ __align__(16) float Bs[16*68];
  int tid = threadIdx.x;
  int tx = tid & 15, ty = tid >> 4;
  int m0 = blockIdx.y * 64, n0 = blockIdx.x * 64;
  int kz = blockIdx.z * kchunk;
  const float* Af = (const float*)Av;
  const bf16*  Ab = (const bf16*)Av;
  float c[4][4] = {};
  for (int k0 = kz; k0 < kz + kchunk; k0 += 16){
    #pragma unroll
    for (int i = 0; i < 4; ++i){
      int idx = tid + i*256;
      int kk = idx & 15, m = idx >> 4;
      size_t aidx = (size_t)(m0+m)*K + k0 + kk;
      float av = a_is_bf16 ? b2f(Ab[aidx]) : Af[aidx];
      if (afold) av = fmaxf(av + afold[k0+kk], 0.f);
      As[kk*68 + m] = av;
    }
    #pragma unroll
    for (int i = 0; i < 4; ++i){
      int idx = tid + i*256;
      int nn = idx & 63, kk = idx >> 6;
      int col = n0 + nn;
      Bs[kk*68 + nn] = (col < N) ? B[(size_t)(k0+kk)*ldb + col] : 0.f;
    }
    __syncthreads();
    #pragma unroll
    for (int kk = 0; kk < 16; ++kk){
      float a[4], b[4];
      *(float4*)a = *(const float4*)&As[kk*68 + ty*4];
      *(float4*)b = *(const float4*)&Bs[kk*68 + tx*4];
      #pragma unroll
      for (int i = 0; i < 4; ++i)
        #pragma unroll
        for (int j = 0; j < 4; ++j)
          c[i][j] += a[i]*b[j];
    }
    __syncthreads();
  }
  #pragma unroll
  for (int i = 0; i < 4; ++i){
    int row = m0 + ty*4 + i;
    #pragma unroll
    for (int j = 0; j < 4; ++j){
      int col = n0 + tx*4 + j;
      if (col < N) atomicAdd(&C[(size_t)row*N + col], c[i][j]);
    }
  }
}

// ---------------- Split-K GEMM, 128x128 tile, 8x8 micro, double-buffered, 1 barrier/k-step ----------
__global__ __launch_bounds__(256) void gemm128_db_kernel(const void* __restrict__ Av, int a_is_bf16,
                                                         const float* __restrict__ B, int ldb,
                                                         float* __restrict__ C,
                                                         int M, int N, int K, int kchunk){
  __shared__ __align__(16) float As[2][16][132];
  __shared__ __align__(16) float Bs[2][16][132];
  int tid = threadIdx.x;
  int tx = tid & 15, ty = tid >> 4;
  int m0 = blockIdx.y * 128, n0 = blockIdx.x * 128;
  int kz = blockIdx.z * kchunk;
  const float* Af = (const float*)Av;
  const bf16*  Ab = (const bf16*)Av;
  const int nsteps = kchunk >> 4;
  float acc[2][2][4][4] = {};

  float4 ra0, ra1, rb0, rb1;
  int4   rab;
  const int ar  = tid >> 2,  akc = (tid & 3) * 4;
  const int abr = tid >> 1,  abk = (tid & 1) * 8;
  const int bkk = tid >> 5,  bnc = (tid & 31) * 4;

  {
    int k0 = kz;
    if (a_is_bf16){
      rab = *(const int4*)(Ab + (size_t)(m0 + abr)*K + k0 + abk);
    } else {
      ra0 = *(const float4*)(Af + (size_t)(m0 + ar     )*K + k0 + akc);
      ra1 = *(const float4*)(Af + (size_t)(m0 + ar + 64)*K + k0 + akc);
    }
    rb0 = *(const float4*)(B + (size_t)(k0 + bkk    )*ldb + n0 + bnc);
    rb1 = *(const float4*)(B + (size_t)(k0 + bkk + 8)*ldb + n0 + bnc);
  }

  for (int s = 0; s < nsteps; ++s){
    const int buf = s & 1;
    if (a_is_bf16){
      unsigned int wv[4] = {(unsigned)rab.x,(unsigned)rab.y,(unsigned)rab.z,(unsigned)rab.w};
      #pragma unroll
      for (int m = 0; m < 4; ++m){
        As[buf][abk + 2*m    ][abr] = bfbits2f(wv[m] & 0xffffu);
        As[buf][abk + 2*m + 1][abr] = bfbits2f(wv[m] >> 16);
      }
    } else {
      As[buf][akc    ][ar]      = ra0.x;
      As[buf][akc + 1][ar]      = ra0.y;
      As[buf][akc + 2][ar]      = ra0.z;
      As[buf][akc + 3][ar]      = ra0.w;
      As[buf][akc    ][ar + 64] = ra1.x;
      As[buf][akc + 1][ar + 64] = ra1.y;
      As[buf][akc + 2][ar + 64] = ra1.z;
      As[buf][akc + 3][ar + 64] = ra1.w;
    }
    *(float4*)&Bs[buf][bkk    ][bnc] = rb0;
    *(float4*)&Bs[buf][bkk + 8][bnc] = rb1;
    __syncthreads();
    if (s + 1 < nsteps){
      int k0 = kz + (s+1)*16;
      if (a_is_bf16){
        rab = *(const int4*)(Ab + (size_t)(m0 + abr)*K + k0 + abk);
      } else {
        ra0 = *(const float4*)(Af + (size_t)(m0 + ar     )*K + k0 + akc);
        ra1 = *(const float4*)(Af + (size_t)(m0 + ar + 64)*K + k0 + akc);
      }
      rb0 = *(const float4*)(B + (size_t)(k0 + bkk    )*ldb + n0 + bnc);
      rb1 = *(const float4*)(B + (size_t)(k0 + bkk + 8)*ldb + n0 + bnc);
    }
    #pragma unroll
    for (int kk = 0; kk < 16; ++kk){
      float4 a0 = *(const float4*)&As[buf][kk][ty*4];
      float4 a1 = *(const float4*)&As[buf][kk][64 + ty*4];
      float4 b0 = *(const float4*)&Bs[buf][kk][tx*4];
      float4 b1 = *(const float4*)&Bs[buf][kk][64 + tx*4];
      float ar2[2][4] = {{a0.x,a0.y,a0.z,a0.w},{a1.x,a1.y,a1.z,a1.w}};
      float br2[2][4] = {{b0.x,b0.y,b0.z,b0.w},{b1.x,b1.y,b1.z,b1.w}};
      #pragma unroll
      for (int hi = 0; hi < 2; ++hi)
        #pragma unroll
        for (int i = 0; i < 4; ++i)
          #pragma unroll
          for (int hj = 0; hj < 2; ++hj)
            #pragma unroll
            for (int j = 0; j < 4; ++j)
              acc[hi][hj][i][j] += ar2[hi][i] * br2[hj][j];
    }
  }
  #pragma unroll
  for (int hi = 0; hi < 2; ++hi)
    #pragma unroll
    for (int i = 0; i < 4; ++i){
      int row = m0 + hi*64 + ty*4 + i;
      #pragma unroll
      for (int hj = 0; hj < 2; ++hj)
        #pragma unroll
        for (int j = 0; j < 4; ++j){
          int col = n0 + hj*64 + tx*4 + j;
          atomicAdd(&C[(size_t)row*N + col], acc[hi][hj][i][j]);
        }
    }
}

// ---------------- Split-K GEMM, 64x128 tile, 8x4 micro, double-buffered (fp32 A only) ---------------
__global__ __launch_bounds__(256) void gemm64_db_kernel(const float* __restrict__ A,
                                                        const float* __restrict__ B, int ldb,
                                                        float* __restrict__ C,
                                                        int M, int N, int K, int kchunk){
  __shared__ __align__(16) float As[2][16][68];
  __shared__ __align__(16) float Bs[2][16][132];
  int tid = threadIdx.x;
  int tx = tid & 31, ty = tid >> 5;
  int m0 = blockIdx.y * 64, n0 = blockIdx.x * 128;
  int kz = blockIdx.z * kchunk;
  const int nsteps = kchunk >> 4;
  float acc[2][4][4] = {};

  float4 ra, rb0, rb1;
  const int ar  = tid >> 2,  akc = (tid & 3) * 4;
  const int bkk = tid >> 5,  bnc = (tid & 31) * 4;

  {
    int k0 = kz;
    ra  = *(const float4*)(A + (size_t)(m0 + ar)*K + k0 + akc);
    rb0 = *(const float4*)(B + (size_t)(k0 + bkk    )*ldb + n0 + bnc);
    rb1 = *(const float4*)(B + (size_t)(k0 + bkk + 8)*ldb + n0 + bnc);
  }

  for (int s = 0; s < nsteps; ++s){
    const int buf = s & 1;
    As[buf][akc    ][ar] = ra.x;
    As[buf][akc + 1][ar] = ra.y;
    As[buf][akc + 2][ar] = ra.z;
    As[buf][akc + 3][ar] = ra.w;
    *(float4*)&Bs[buf][bkk    ][bnc] = rb0;
    *(float4*)&Bs[buf][bkk + 8][bnc] = rb1;
    __syncthreads();
    if (s + 1 < nsteps){
      int k0 = kz + (s+1)*16;
      ra  = *(const float4*)(A + (size_t)(m0 + ar)*K + k0 + akc);
      rb0 = *(const float4*)(B + (size_t)(k0 + bkk    )*ldb + n0 + bnc);
      rb1 = *(const float4*)(B + (size_t)(k0 + bkk + 8)*ldb + n0 + bnc);
    }
    #pragma unroll
    for (int kk = 0; kk < 16; ++kk){
      float4 a0 = *(const float4*)&As[buf][kk][ty*4];
      float4 a1 = *(const float4*)&As[buf][kk][32 + ty*4];
      float4 b  = *(const float4*)&Bs[buf][kk][tx*4];
      float ar2[2][4] = {{a0.x,a0.y,a0.z,a0.w},{a1.x,a1.y,a1.z,a1.w}};
      float br2[4]    = {b.x,b.y,b.z,b.w};
      #pragma unroll
      for (int q = 0; q < 2; ++q)
        #pragma unroll
        for (int i = 0; i < 4; ++i)
          #pragma unroll
          for (int j = 0; j < 4; ++j)
            acc[q][i][j] += ar2[q][i] * br2[j];
    }
  }
  #pragma unroll
  for (int q = 0; q < 2; ++q)
    #pragma unroll
    for (int i = 0; i < 4; ++i){
      int row = m0 + q*32 + ty*4 + i;
      #pragma unroll
      for (int j = 0; j < 4; ++j){
        int col = n0 + tx*4 + j;
        atomicAdd(&C[(size_t)row*N + col], acc[q][i][j]);
      }
    }
}

// ---------------- out-GEMM via bf16 MFMA with hi/lo-split B (near-fp32 exact) -----------------------
// C[1024][2048] = A(bf16)[1024][2048] @ B(fp32)[2048][2048]
// B is split on the fly: B = Bhi + Blo (both bf16), residual ~2^-18 relative -> numerics ~fp32.
// Tiles: 64(M) x 128(N), grid (16,16) = 256 WGs = 1 WG/CU, 4 waves, wave owns 64x32.
// Per 32-K slab per wave: 4 A-frags (direct from global, reg-prefetched), 2 B col-frags
// (8 scalar LDS fp32 reads each + in-reg cvt to hi/lo bf16x8), 16 MFMA (8 frags x hi/lo).
// MFMA 16x16x32 bf16 layouts: A lane: row=l&15, k=(l>>4)*8+e; B lane: col=l&15, k=(l>>4)*8+e;
// D lane: col=l&15, row=(l>>4)*4+r  [m89-verified].
// No split-K, no atomics: direct fp32 stores. Single barrier per slab (dbuf, same proof as above).
__global__ __launch_bounds__(256) void gemm_mfma_out_kernel(const bf16* __restrict__ A,
                                                            const float* __restrict__ B,
                                                            float* __restrict__ C){
  const int n0 = blockIdx.x * 128;
  const int m0 = blockIdx.y * 64;
  const int tid = threadIdx.x;
  const int wid = tid >> 6, lane = tid & 63;
  const int l15 = lane & 15, lg = lane >> 4;      // lane-group 0..3 -> k-offset lg*8
  const int wc = wid * 32;                        // wave's col base within tile
  __shared__ __align__(16) float Bs[2][32][133];  // [kk][col], pad 133 -> 2-way max on frag reads

  // B staging: thread t covers kk = t>>3, cols (t&7)*4 + i*32 + {0..3} (i=0..3) — coalesced
  const int skk = tid >> 3, sc4 = (tid & 7) * 4;

  f32x4 acc[4][2];
  #pragma unroll
  for (int m = 0; m < 4; ++m)
    #pragma unroll
    for (int nf = 0; nf < 2; ++nf)
      acc[m][nf] = (f32x4){0.f,0.f,0.f,0.f};

  float4 rb[4];
  int4   rafr[4];
  {
    const int k0 = 0;
    #pragma unroll
    for (int i = 0; i < 4; ++i)
      rb[i] = *(const float4*)(B + (size_t)(k0 + skk)*DIM + n0 + sc4 + i*32);
    #pragma unroll
    for (int m = 0; m < 4; ++m)
      rafr[m] = *(const int4*)(A + (size_t)(m0 + m*16 + l15)*DIM + k0 + lg*8);
  }

  for (int s = 0; s < 64; ++s){
    const int buf = s & 1;
    // commit staged B to LDS
    #pragma unroll
    for (int i = 0; i < 4; ++i)
      *(float4*)&Bs[buf][skk][sc4 + i*32] = rb[i];
    // current A frags
    int4 afr[4];
    #pragma unroll
    for (int m = 0; m < 4; ++m) afr[m] = rafr[m];
    __syncthreads();
    // prefetch next slab
    if (s + 1 < 64){
      const int k0 = (s+1)*32;
      #pragma unroll
      for (int i = 0; i < 4; ++i)
        rb[i] = *(const float4*)(B + (size_t)(k0 + skk)*DIM + n0 + sc4 + i*32);
      #pragma unroll
      for (int m = 0; m < 4; ++m)
        rafr[m] = *(const int4*)(A + (size_t)(m0 + m*16 + l15)*DIM + k0 + lg*8);
    }
    // compute
    #pragma unroll
    for (int nf = 0; nf < 2; ++nf){
      const int col = wc + nf*16 + l15;
      float bv[8];
      #pragma unroll
      for (int j = 0; j < 8; ++j) bv[j] = Bs[buf][lg*8 + j][col];
      bf16x8 bh, bl;
      #pragma unroll
      for (int j = 0; j < 8; ++j){
        unsigned short h = f2bf(bv[j]);
        float hf = bfbits2f(h);
        unsigned short l = f2bf(bv[j] - hf);
        bh[j] = (short)h;
        bl[j] = (short)l;
      }
      #pragma unroll
      for (int m = 0; m < 4; ++m){
        union { int4 i; bf16x8 v; } ua; ua.i = afr[m];
        acc[m][nf] = __builtin_amdgcn_mfma_f32_16x16x32_bf16(ua.v, bh, acc[m][nf], 0, 0, 0);
        acc[m][nf] = __builtin_amdgcn_mfma_f32_16x16x32_bf16(ua.v, bl, acc[m][nf], 0, 0, 0);
      }
    }
  }
  // epilogue: direct stores (no atomics)
  #pragma unroll
  for (int m = 0; m < 4; ++m)
    #pragma unroll
    for (int nf = 0; nf < 2; ++nf){
      const int col = n0 + wc + nf*16 + l15;
      #pragma unroll
      for (int r = 0; r < 4; ++r){
        const int row = m0 + m*16 + lg*4 + r;
        C[(size_t)row*DIM + col] = acc[m][nf][r];
      }
    }
}

// ---------------- RoPE: q fp32 [n][2048], kv fp32 [n][512] -> qr bf16 [n][2048], kr bf16 [n][256] ----
__global__ __launch_bounds__(256) void rope_kernel(const float* __restrict__ q,
    const float* __restrict__ kv, bf16* __restrict__ qr, bf16* __restrict__ kr){
  int n = blockIdx.x, tid = threadIdx.x;
  const float* qrow = q + (size_t)n*DIM;
  bf16* qrrow = qr + (size_t)n*DIM;
  #pragma unroll
  for (int i = 0; i < 4; ++i){
    int p = tid + i*256;
    int hd = p >> 6, ii = p & 63;
    float inv = powf(10000.f, -(float)ii/64.f);
    float ang = (float)n * inv;
    float cs = cosf(ang), sn = sinf(ang);
    float x1 = qrow[hd*DH + 2*ii], x2 = qrow[hd*DH + 2*ii + 1];
    qrrow[hd*DH + 2*ii]     = __float2bfloat16(x1*cs - x2*sn);
    qrrow[hd*DH + 2*ii + 1] = __float2bfloat16(x1*sn + x2*cs);
  }
  if (tid < 128){
    int h = tid >> 6, ii = tid & 63;
    float inv = powf(10000.f, -(float)ii/64.f);
    float ang = (float)n * inv;
    float cs = cosf(ang), sn = sinf(ang);
    const float* kvrow = kv + (size_t)n*512;
    float x1 = kvrow[h*DH + 2*ii], x2 = kvrow[h*DH + 2*ii + 1];
    bf16* krrow = kr + (size_t)n*256;
    krrow[h*DH + 2*ii]     = __float2bfloat16(x1*cs - x2*sn);
    krrow[h*DH + 2*ii + 1] = __float2bfloat16(x1*sn + x2*cs);
  }
}

// ---------------- Build compression-MLP input f [128][CDIM] (k: voff=0, v: voff=256) ----------------
__global__ __launch_bounds__(256) void build_f_kernel(const float* __restrict__ kv, int voff,
    const float* __restrict__ pos, float* __restrict__ f){
  int bw = blockIdx.x;           // h*NWIN + w
  int h = bw >> 6, w = bw & 63;
  int tid = threadIdx.x;
  for (int idx = tid; idx < CMP_BLK*DH; idx += 256){
    int j = idx >> 7, d = idx & 127;
    int t = w*16 + j - 16;       // padded window index
    float kvv = (t >= 0) ? kv[(size_t)t*512 + voff + h*DH + d] : 0.f;
    f[(size_t)bw*CDIM + idx] = kvv + pos[(h*CMP_BLK + j)*DH + d];
  }
}

// ---------------- Assemble ck/cv [KVH][NCMP][DH]; MLP second bias folded here ----------------
__global__ __launch_bounds__(256) void assemble_kernel(const float* __restrict__ ckb,
    const float* __restrict__ cvb, const float* __restrict__ mem_kv,
    const float* __restrict__ bk2, const float* __restrict__ bv2,
    float* __restrict__ ck, float* __restrict__ cv){
  int j = blockIdx.x;            // 0..64
  int tid = threadIdx.x;         // 256 = KVH*DH
  int h = tid >> 7, d = tid & 127;
  float kvx, vvx;
  if (j == 0){
    kvx = mem_kv[(0*KVH + h)*DH + d];
    vvx = mem_kv[(1*KVH + h)*DH + d];
  } else {
    kvx = ckb[((size_t)h*NWIN + (j-1))*DH + d] + bk2[d];
    vvx = cvb[((size_t)h*NWIN + (j-1))*DH + d] + bv2[d];
  }
  ck[((size_t)h*NCMP + j)*DH + d] = kvx;
  cv[((size_t)h*NCMP + j)*DH + d] = vvx;
}

// ---------------- Compressed attention (pre-rope q, fp32) + importance + top-4 selection ----------------
__global__ __launch_bounds__(256) void cmp_attn_kernel(const float* __restrict__ q,
    const float* __restrict__ ck, const float* __restrict__ cv,
    bf16* __restrict__ cmp_o, int* __restrict__ sel){
  int bx = blockIdx.x;
  int h = bx >> 10, n = bx & 1023;
  int tid = threadIdx.x;
  __shared__ float cks[NCMP*129];
  __shared__ float qs[GQ*DH];
  __shared__ float sims[GQ*66];
  __shared__ float red[GQ*32];
  __shared__ float impb[NFINE];
  for (int idx = tid; idx < NCMP*DH; idx += 256){
    int j = idx >> 7, d = idx & 127;
    cks[j*129 + d] = ck[((size_t)h*NCMP + j)*DH + d];
  }
  for (int idx = tid; idx < GQ*DH; idx += 256)
    qs[idx] = q[(size_t)n*DIM + h*(GQ*DH) + idx];
  __syncthreads();
  for (int p = tid; p < GQ*NCMP; p += 256){
    int g = p / NCMP, j = p % NCMP;
    float acc = 0.f;
    const float* qp = &qs[g*DH];
    const float* kp = &cks[j*129];
    #pragma unroll 4
    for (int d = 0; d < DH; ++d) acc += qp[d]*kp[d];
    sims[g*66 + j] = acc * SCALE;
  }
  __syncthreads();
  if (tid < NFINE){
    float s = 0.f;
    for (int g = 0; g < GQ; ++g)
      #pragma unroll
      for (int c = 0; c < 4; ++c)
        s += sims[g*66 + 1 + tid*4 + c];
    impb[tid] = s;
  }
  __syncthreads();
  if (tid == 0){
    int own = n >> 6;
    impb[own] = -1e30f;
    int selbuf[5];
    #pragma unroll
    for (int r = 0; r < 4; ++r){
      float best = -1e38f; int bi = 0;
      for (int f = 0; f < NFINE; ++f)
        if (impb[f] > best){ best = impb[f]; bi = f; }   // strict > : lowest index on ties
      selbuf[r] = bi; impb[bi] = -1e38f;
    }
    selbuf[4] = own;
    for (int r = 0; r < 5; ++r) sel[(size_t)(h*N_TOK + n)*8 + r] = selbuf[r];
  }
  int g = tid >> 5, lane = tid & 31;
  float m = -1e38f;
  for (int j = lane; j < NCMP; j += 32) m = fmaxf(m, sims[g*66 + j]);
  red[g*32 + lane] = m; __syncthreads();
  for (int st = 16; st > 0; st >>= 1){ if (lane < st) red[g*32+lane] = fmaxf(red[g*32+lane], red[g*32+lane+st]); __syncthreads(); }
  float gm = red[g*32]; __syncthreads();
  float ps = 0.f;
  for (int j = lane; j < NCMP; j += 32){ float e = expf(sims[g*66+j] - gm); sims[g*66+j] = e; ps += e; }
  red[g*32+lane] = ps; __syncthreads();
  for (int st = 16; st > 0; st >>= 1){ if (lane < st) red[g*32+lane] += red[g*32+lane+st]; __syncthreads(); }
  float inv = 1.f / red[g*32]; __syncthreads();
  for (int j = lane; j < NCMP; j += 32) sims[g*66+j] *= inv;
  __syncthreads();
  for (int p = tid; p < GQ*DH; p += 256){
    int gg = p >> 7, d = p & 127;
    float acc = 0.f;
    const float* cvp = cv + (size_t)h*NCMP*DH + d;
    for (int j = 0; j < NCMP; ++j) acc += sims[gg*66 + j] * cvp[j*DH];
    cmp_o[(size_t)n*DIM + (h*GQ + gg)*DH + d] = __float2bfloat16(acc);
  }
}

// ---------------- Fine (selected-block) attention: roped q/k (bf16), raw v (fp32 strided) ------------
__global__ __launch_bounds__(256) void fine_attn_kernel(const bf16* __restrict__ qr,
    const bf16* __restrict__ kr, const float* __restrict__ kv,
    const int* __restrict__ sel, bf16* __restrict__ fine_o){
  int bx = blockIdx.x;
  int h = bx >> 10, n = bx & 1023;
  int tid = threadIdx.x;
  __shared__ float kt[SEL_BLK*129];
  __shared__ float qs[GQ*DH];
  __shared__ float sims[GQ*321];
  __shared__ float red[GQ*32];
  int sel5[5];
  #pragma unroll
  for (int r = 0; r < 5; ++r){
    int b = sel[(size_t)(h*N_TOK + n)*8 + r];
    sel5[r] = (b < 0) ? 0 : (b > 15 ? 15 : b);
  }
  for (int idx = tid; idx < GQ*DH; idx += 256)
    qs[idx] = b2f(qr[(size_t)n*DIM + h*(GQ*DH) + idx]);
  for (int tile = 0; tile < 5; ++tile){
    int blk = sel5[tile];
    __syncthreads();
    for (int idx = tid; idx < SEL_BLK*DH; idx += 256){
      int tl = idx >> 7, d = idx & 127;
      kt[tl*129 + d] = b2f(kr[(size_t)(blk*SEL_BLK + tl)*256 + h*DH + d]);
    }
    __syncthreads();
    for (int p = tid; p < GQ*SEL_BLK; p += 256){
      int g = p >> 6, t = p & 63;
      float acc = 0.f;
      const float* qp = &qs[g*DH];
      const float* kp = &kt[t*129];
      #pragma unroll 4
      for (int d = 0; d < DH; ++d) acc += qp[d]*kp[d];
      sims[g*321 + tile*SEL_BLK + t] = acc * SCALE;
    }
  }
  __syncthreads();
  int g = tid >> 5, lane = tid & 31;
  float m = -1e38f;
  for (int t = lane; t < T_TOT; t += 32) m = fmaxf(m, sims[g*321 + t]);
  red[g*32+lane] = m; __syncthreads();
  for (int st = 16; st > 0; st >>= 1){ if (lane < st) red[g*32+lane] = fmaxf(red[g*32+lane], red[g*32+lane+st]); __syncthreads(); }
  float gm = red[g*32]; __syncthreads();
  float ps = 0.f;
  for (int t = lane; t < T_TOT; t += 32){ float e = expf(sims[g*321+t] - gm); sims[g*321+t] = e; ps += e; }
  red[g*32+lane] = ps; __syncthreads();
  for (int st = 16; st > 0; st >>= 1){ if (lane < st) red[g*32+lane] += red[g*32+lane+st]; __syncthreads(); }
  float inv = 1.f / red[g*32]; __syncthreads();
  for (int t = lane; t < T_TOT; t += 32) sims[g*321+t] *= inv;
  float acc[4] = {0.f,0.f,0.f,0.f};
  for (int tile = 0; tile < 5; ++tile){
    int blk = sel5[tile];
    __syncthreads();
    for (int idx = tid; idx < SEL_BLK*DH; idx += 256){
      int tl = idx >> 7, d = idx & 127;
      kt[tl*129 + d] = kv[(size_t)(blk*SEL_BLK + tl)*512 + 256 + h*DH + d];
    }
    __syncthreads();
    #pragma unroll
    for (int i = 0; i < 4; ++i){
      int p = tid + i*256;
      int gg = p >> 7, d = p & 127;
      float a = acc[i];
      const float* sp = &sims[gg*321 + tile*SEL_BLK];
      const float* vp = &kt[d];
      for (int t = 0; t < SEL_BLK; ++t) a += sp[t]*vp[t*129];
      acc[i] = a;
    }
  }
  #pragma unroll
  for (int i = 0; i < 4; ++i){
    int p = tid + i*256;
    int gg = p >> 7, d = p & 127;
    fine_o[(size_t)n*DIM + (h*GQ + gg)*DH + d] = __float2bfloat16(acc[i]);
  }
}

// ---------------- Sliding-window attention, flash-style online softmax --------------------------
__global__ __launch_bounds__(256) void slide_attn_kernel(const bf16* __restrict__ qr,
    const bf16* __restrict__ kr, const float* __restrict__ kv,
    bf16* __restrict__ slide_o){
  int hq = blockIdx.y;          // 16 heads
  int qt = blockIdx.x;          // 32 query tiles of 32
  int h = hq >> 3;
  int n0 = qt * 32;
  int tid = threadIdx.x;
  __shared__ float qT[128*36];   // [d][qi], pad 36
  __shared__ float kvb[128*68];  // K^T [d][t] pad 68 (QK) | V [t][128] (PV)
  __shared__ float stT[64*36];   // [t][qi] exp'd probs, pad 36

  const int ty  = tid >> 5;
  const int tx  = tid & 31;
  const int qi0 = ty << 2;

  for (int c = tid; c < 512; c += 256){
    int qi = c & 31, d0 = (c >> 5) << 3;
    int4 w = *(const int4*)(qr + (size_t)(n0+qi)*DIM + hq*DH + d0);
    float* dst = &qT[(size_t)d0*36 + qi];
    unsigned int wv[4] = {(unsigned)w.x,(unsigned)w.y,(unsigned)w.z,(unsigned)w.w};
    #pragma unroll
    for (int m = 0; m < 4; ++m){
      dst[(2*m  )*36] = bfbits2f(wv[m] & 0xffffu);
      dst[(2*m+1)*36] = bfbits2f(wv[m] >> 16);
    }
  }

  float acc[4][4] = {};
  float mrow[4] = {-1e30f,-1e30f,-1e30f,-1e30f};
  float lrow[4] = {0.f,0.f,0.f,0.f};
  float arow[4];
  const int kstart = n0 - 128;

  for (int tile = 0; tile < 5; ++tile){
    const int kbase = kstart + tile*64;
    __syncthreads();
    for (int c = tid; c < 1024; c += 256){
      int t = c & 63, d0 = (c >> 6) << 3;
      int kg = kbase + t;
      int kgc = min(max(kg, 0), N_TOK-1);
      int4 w = *(const int4*)(kr + (size_t)kgc*256 + h*DH + d0);
      float* dst = &kvb[(size_t)d0*68 + t];
      unsigned int wv[4] = {(unsigned)w.x,(unsigned)w.y,(unsigned)w.z,(unsigned)w.w};
      #pragma unroll
      for (int m = 0; m < 4; ++m){
        dst[(2*m  )*68] = bfbits2f(wv[m] & 0xffffu);
        dst[(2*m+1)*68] = bfbits2f(wv[m] >> 16);
      }
    }
    __syncthreads();
    float c0[8] = {};
    {
      const float* aP = qT + qi0;
      const float* bP = kvb + (tx << 1);
      #pragma unroll 4
      for (int d = 0; d < 128; ++d){
        float4 a = *(const float4*)(aP + d*36);
        float2 b = *(const float2*)(bP + d*68);
        c0[0] += a.x*b.x; c0[1] += a.x*b.y;
        c0[2] += a.y*b.x; c0[3] += a.y*b.y;
        c0[4] += a.z*b.x; c0[5] += a.z*b.y;
        c0[6] += a.w*b.x; c0[7] += a.w*b.y;
      }
    }
    const int kg0 = kbase + (tx << 1);
    #pragma unroll
    for (int i = 0; i < 4; ++i){
      int qg = n0 + qi0 + i;
      int d0 = qg - kg0, d1 = d0 - 1;
      bool v0 = (kg0   >= 0) && (kg0   < N_TOK) && (d0 <= 128) && (d0 >= -128);
      bool v1 = (kg0+1 >= 0) && (kg0+1 < N_TOK) && (d1 <= 128) && (d1 >= -128);
      float s0 = v0 ? c0[i*2  ]*SCALE : -1e30f;
      float s1 = v1 ? c0[i*2+1]*SCALE : -1e30f;
      float mi = fmaxf(s0, s1);
      #pragma unroll
      for (int off = 1; off < 32; off <<= 1) mi = fmaxf(mi, __shfl_xor(mi, off));
      float mold = mrow[i];
      float mnew = fmaxf(fmaxf(mold, mi), -1e20f);
      arow[i] = expf(mold - mnew);
      mrow[i] = mnew;
      float e0 = expf(s0 - mnew);
      float e1 = expf(s1 - mnew);
      float ps = e0 + e1;
      #pragma unroll
      for (int off = 1; off < 32; off <<= 1) ps += __shfl_xor(ps, off);
      lrow[i] = lrow[i]*arow[i] + ps;
      stT[(size_t)(2*tx  )*36 + qi0 + i] = e0;
      stT[(size_t)(2*tx+1)*36 + qi0 + i] = e1;
    }
    __syncthreads();
    for (int c = tid; c < 2048; c += 256){
      int t = c >> 5, d0 = (c & 31) << 2;
      int kg = kbase + t;
      int kgc = min(max(kg, 0), N_TOK-1);
      float4 v = *(const float4*)(kv + (size_t)kgc*512 + 256 + h*DH + d0);
      *(float4*)&kvb[(size_t)t*128 + d0] = v;
    }
    __syncthreads();
    #pragma unroll
    for (int i = 0; i < 4; ++i){
      float ar = arow[i];
      acc[i][0] *= ar; acc[i][1] *= ar; acc[i][2] *= ar; acc[i][3] *= ar;
    }
    {
      const float* pP = stT + qi0;
      const float* vP = kvb + (tx << 2);
      #pragma unroll 4
      for (int t = 0; t < 64; ++t){
        float4 p = *(const float4*)(pP + t*36);
        float4 v = *(const float4*)(vP + t*128);
        acc[0][0] += p.x*v.x; acc[0][1] += p.x*v.y; acc[0][2] += p.x*v.z; acc[0][3] += p.x*v.w;
        acc[1][0] += p.y*v.x; acc[1][1] += p.y*v.y; acc[1][2] += p.y*v.z; acc[1][3] += p.y*v.w;
        acc[2][0] += p.z*v.x; acc[2][1] += p.z*v.y; acc[2][2] += p.z*v.z; acc[2][3] += p.z*v.w;
        acc[3][0] += p.w*v.x; acc[3][1] += p.w*v.y; acc[3][2] += p.w*v.z; acc[3][3] += p.w*v.w;
      }
    }
  }
  #pragma unroll
  for (int i = 0; i < 4; ++i){
    int row = n0 + qi0 + i;
    float inv = 1.f / lrow[i];
    bf16 o[4];
    o[0] = __float2bfloat16(acc[i][0]*inv);
    o[1] = __float2bfloat16(acc[i][1]*inv);
    o[2] = __float2bfloat16(acc[i][2]*inv);
    o[3] = __float2bfloat16(acc[i][3]*inv);
    *(ushort4*)(slide_o + (size_t)row*DIM + hq*DH + (tx << 2)) = *(const ushort4*)o;
  }
}

// ---------------- Gated combine; gate bias+sigmoid folded here -> ocomb bf16 [n][2048] --------------
__global__ __launch_bounds__(256) void combine_kernel(const bf16* __restrict__ cmp_o,
    const bf16* __restrict__ fine_o, const bf16* __restrict__ slide_o,
    const float* __restrict__ graw, const float* __restrict__ bg,
    bf16* __restrict__ ocomb){
  int n = blockIdx.x, tid = threadIdx.x;
  #pragma unroll
  for (int i = 0; i < 8; ++i){
    int c = tid + i*256;
    int hq = c >> 7;
    float g0 = 1.f/(1.f + expf(-(graw[(size_t)n*48 + hq*3 + 0] + bg[hq*3 + 0])));
    float g1 = 1.f/(1.f + expf(-(graw[(size_t)n*48 + hq*3 + 1] + bg[hq*3 + 1])));
    float g2 = 1.f/(1.f + expf(-(graw[(size_t)n*48 + hq*3 + 2] + bg[hq*3 + 2])));
    size_t idx = (size_t)n*DIM + c;
    ocomb[idx] = __float2bfloat16(b2f(cmp_o[idx])*g0 + b2f(fine_o[idx])*g1 + b2f(slide_o[idx])*g2);
  }
}

extern "C" void kernel_launch(void* const* d_in, const int* in_sizes, int n_in,
                              void* d_out, int out_size, void* d_ws, size_t ws_size,
                              hipStream_t stream)
{
  const float* x      = (const float*)d_in[0];
  const float* g_norm = (const float*)d_in[1];
  const float* W_qkv  = (const float*)d_in[2];
  const float* k_pos  = (const float*)d_in[3];
  const float* v_pos  = (const float*)d_in[4];
  const float* mem_kv = (const float*)d_in[5];
  const float* Wk1    = (const float*)d_in[6];
  const float* bk1    = (const float*)d_in[7];
  const float* Wk2    = (const float*)d_in[8];
  const float* bk2    = (const float*)d_in[9];
  const float* Wv1    = (const float*)d_in[10];
  const float* bv1    = (const float*)d_in[11];
  const float* Wv2    = (const float*)d_in[12];
  const float* bv2    = (const float*)d_in[13];
  const float* Wg     = (const float*)d_in[14];
  const float* bg     = (const float*)d_in[15];
  const float* W_out  = (const float*)d_in[16];
  float* out = (float*)d_out;
  (void)ws_size; (void)in_sizes; (void)n_in; (void)out_size;

  // ---- Workspace layout (bytes), total ~23.6 MB, aggressive region reuse ----
  char* base = (char*)d_ws;
  float* q     = (float*)(base + 0);                 // 8 MB [n][2048] fp32, live -> cmp_attn
  float* xn    = (float*)(base + 8388608);           // 8 MB fp32, live -> kv GEMM
  bf16*  qr    = (bf16*) (base + 8388608);           // 4 MB (over xn, after xn dead)
  bf16*  kr    = (bf16*) (base + 12582912);          // 0.5 MB
  bf16*  ocomb = (bf16*) (base + 8388608);           // 4 MB (over qr, after slide)
  float* kv    = (float*)(base + 16777216);          // 2 MB [n][512] fp32
  float* fbuf  = (float*)(base + 18874368);          // 2 MB fk / fv
  float* hbuf  = (float*)(base + 20971520);          // 2 MB hk / hv (raw, bias folded downstream)
  bf16*  cmp_o = (bf16*) (base + 18874368);          // 4 MB (over fbuf+hbuf, after MLPs)
  float* ckb   = (float*)(base + 23068672);          // 64 KB (raw)
  float* cvb   = (float*)(base + 23134208);          // 64 KB (raw)
  float* ck    = (float*)(base + 23199744);          // 65 KB
  float* cv    = (float*)(base + 23266304);          // 65 KB
  float* gates = (float*)(base + 23332864);          // 192 KB (raw, sigmoid folded in combine)
  int*   sel   = (int*)  (base + 23529472);          // 64 KB   (end: 23,595,008 B)
  bf16*  fine_o  = (bf16*)(base + 0);                // 4 MB (over q, after cmp_attn)
  bf16*  slide_o = (bf16*)(base + 4194304);          // 4 MB (over q upper half)

  // Zero split-K accumulation targets (stream-ordered; graph-capture legal)
  hipMemsetAsync(q,     0, (size_t)N_TOK*DIM*4,  stream);
  hipMemsetAsync(kv,    0, (size_t)N_TOK*512*4,  stream);
  hipMemsetAsync(gates, 0, (size_t)N_TOK*48*4,   stream);
  hipMemsetAsync(ckb,   0, (size_t)KVH*NWIN*DH*4, stream);
  hipMemsetAsync(cvb,   0, (size_t)KVH*NWIN*DH*4, stream);

  rmsnorm_kernel<<<N_TOK, 256, 0, stream>>>(x, g_norm, xn);
  // gates_raw = xn @ Wg            [1024 x 48],  small -> old 64x64 kernel
  gemm_splitk_kernel<<<dim3(1, 16, 8), 256, 0, stream>>>(xn, 0, nullptr, Wg, 48, gates, N_TOK, 48, DIM, 256);
  // q = xn @ W_qkv[:, 0:2048]      [1024 x 2048], 128x128 dbuf, kchunk=512 (values match old)
  gemm128_db_kernel<<<dim3(16, 8, 4), 256, 0, stream>>>(xn, 0, W_qkv, 2560, q, N_TOK, 2048, DIM, 512);
  // kv = xn @ W_qkv[:, 2048:2560]  [1024 x 512], 64x128 dbuf, kchunk=256 (values match old)
  gemm64_db_kernel<<<dim3(4, 16, 8), 256, 0, stream>>>(xn, W_qkv + 2048, 2560, kv, N_TOK, 512, DIM, 256);
  // qr, kr (bf16) — xn now dead
  rope_kernel<<<N_TOK, 256, 0, stream>>>(q, kv, qr, kr);
  // compression MLPs (fp32, selection-critical via ck). relu(.+bk1) folded into MLP2 A-load; bk2 into assemble.
  build_f_kernel<<<KVH*NWIN, 256, 0, stream>>>(kv, 0, k_pos, fbuf);
  hipMemsetAsync(hbuf, 0, (size_t)KVH*NWIN*CDIM*4, stream);
  gemm64_db_kernel<<<dim3(32, 2, 8), 256, 0, stream>>>(fbuf, Wk1, CDIM, hbuf, KVH*NWIN, CDIM, CDIM, 512);
  gemm_splitk_kernel<<<dim3(2, 2, 32),  256, 0, stream>>>(hbuf, 0, bk1,     Wk2, DH,   ckb,  KVH*NWIN, DH,   CDIM, 128);
  build_f_kernel<<<KVH*NWIN, 256, 0, stream>>>(kv, 256, v_pos, fbuf);
  hipMemsetAsync(hbuf, 0, (size_t)KVH*NWIN*CDIM*4, stream);
  gemm64_db_kernel<<<dim3(32, 2, 8), 256, 0, stream>>>(fbuf, Wv1, CDIM, hbuf, KVH*NWIN, CDIM, CDIM, 512);
  gemm_splitk_kernel<<<dim3(2, 2, 32),  256, 0, stream>>>(hbuf, 0, bv1,     Wv2, DH,   cvb,  KVH*NWIN, DH,   CDIM, 128);
  assemble_kernel<<<NCMP, 256, 0, stream>>>(ckb, cvb, mem_kv, bk2, bv2, ck, cv);
  // compressed attention + selection (fbuf/hbuf dead -> cmp_o)
  cmp_attn_kernel<<<KVH*N_TOK, 256, 0, stream>>>(q, ck, cv, cmp_o, sel);
  // fine attention (q dead -> fine_o over q region)
  fine_attn_kernel<<<KVH*N_TOK, 256, 0, stream>>>(qr, kr, kv, sel, fine_o);
  // sliding attention (-> slide_o over q upper half)
  slide_attn_kernel<<<dim3(32, 16), 256, 0, stream>>>(qr, kr, kv, slide_o);
  // combine (qr dead -> ocomb over qr); sigmoid(graw+bg) folded here
  combine_kernel<<<N_TOK, 256, 0, stream>>>(cmp_o, fine_o, slide_o, gates, bg, ocomb);
  // out = ocomb @ W_out via bf16 MFMA with hi/lo-split B (near-fp32 exact, no atomics, direct stores)
  gemm_mfma_out_kernel<<<dim3(16, 16), 256, 0, stream>>>(ocomb, W_out, out);
}

// Round 5
// 1074.065 us; speedup vs baseline: 1.2651x; 1.0783x over previous
//
#include <hip/hip_runtime.h>
#include <hip/hip_bf16.h>
#include <math.h>

typedef __hip_bfloat16 bf16;
typedef __attribute__((ext_vector_type(8))) short bf16x8;
typedef __attribute__((ext_vector_type(4))) float f32x4;

#define N_TOK 1024
#define DIM 2048
#define NHEADS 16
#define KVH 2
#define DH 128
#define GQ 8
#define NWIN 64
#define CMP_BLK 32
#define NCMP 65        // MEM_KV + NWIN
#define NFINE 16
#define SEL_BLK 64
#define T_TOT 320
#define CDIM 4096      // CMP_BLK*DH
#define SCALE 0.08838834764831845f

static __device__ __forceinline__ float b2f(bf16 v){ return __bfloat162float(v); }
static __device__ __forceinline__ float bfbits2f(unsigned int u){
  union { unsigned int i; float f; } x; x.i = u << 16; return x.f;
}
// RNE float->bf16 bits (matches __float2bfloat16 for normal values)
static __device__ __forceinline__ unsigned short f2bf(float f){
  union { float f; unsigned u; } x; x.f = f;
  unsigned r = x.u + 0x7fffu + ((x.u >> 16) & 1u);
  return (unsigned short)(r >> 16);
}

// ---------------- RMSNorm: x fp32 [N,DIM] -> xn fp32 ----------------
__global__ __launch_bounds__(256) void rmsnorm_kernel(const float* __restrict__ x,
                                                      const float* __restrict__ g,
                                                      float* __restrict__ xn){
  int n = blockIdx.x, tid = threadIdx.x;
  __shared__ float red[256];
  const float* row = x + (size_t)n*DIM;
  float vals[8];
  float s = 0.f;
  #pragma unroll
  for (int i = 0; i < 8; ++i){ float v = row[tid + i*256]; vals[i] = v; s += v*v; }
  red[tid] = s; __syncthreads();
  for (int st = 128; st > 0; st >>= 1){ if (tid < st) red[tid] += red[tid+st]; __syncthreads(); }
  float scale = 1.0f / sqrtf(red[0]/(float)DIM + 1e-6f);
  #pragma unroll
  for (int i = 0; i < 8; ++i){
    int c = tid + i*256;
    xn[(size_t)n*DIM + c] = vals[i]*scale*g[c];
  }
}

// ---------------- Split-K GEMM (64x64 tile) — kept for the small shapes (gates, MLP2) --------------
__global__ __launch_bounds__(256) void gemm_splitk_kernel(const void* __restrict__ Av, int a_is_bf16,
                                                          const float* __restrict__ afold,
                                                          const float* __restrict__ B, int ldb,
                                                          float* __restrict__ C,
                                                          int M, int N, int K, int kchunk){
  __shared__ __align__(16) float As[16*68];
  __shared__ __align__(16) float Bs[16*68];
  int tid = threadIdx.x;
  int tx = tid & 15, ty = tid >> 4;
  int m0 = blockIdx.y * 64, n0 = blockIdx.x * 64;
  int kz = blockIdx.z * kchunk;
  const float* Af = (const float*)Av;
  const bf16*  Ab = (const bf16*)Av;
  float c[4][4] = {};
  for (int k0 = kz; k0 < kz + kchunk; k0 += 16){
    #pragma unroll
    for (int i = 0; i < 4; ++i){
      int idx = tid + i*256;
      int kk = idx & 15, m = idx >> 4;
      size_t aidx = (size_t)(m0+m)*K + k0 + kk;
      float av = a_is_bf16 ? b2f(Ab[aidx]) : Af[aidx];
      if (afold) av = fmaxf(av + afold[k0+kk], 0.f);
      As[kk*68 + m] = av;
    }
    #pragma unroll
    for (int i = 0; i < 4; ++i){
      int idx = tid + i*256;
      int nn = idx & 63, kk = idx >> 6;
      int col = n0 + nn;
      Bs[kk*68 + nn] = (col < N) ? B[(size_t)(k0+kk)*ldb + col] : 0.f;
    }
    __syncthreads();
    #pragma unroll
    for (int kk = 0; kk < 16; ++kk){
      float a[4], b[4];
      *(float4*)a = *(const float4*)&As[kk*68 + ty*4];
      *(float4*)b = *(const float4*)&Bs[kk*68 + tx*4];
      #pragma unroll
      for (int i = 0; i < 4; ++i)
        #pragma unroll
        for (int j = 0; j < 4; ++j)
          c[i][j] += a[i]*b[j];
    }
    __syncthreads();
  }
  #pragma unroll
  for (int i = 0; i < 4; ++i){
    int row = m0 + ty*4 + i;
    #pragma unroll
    for (int j = 0; j < 4; ++j){
      int col = n0 + tx*4 + j;
      if (col < N) atomicAdd(&C[(size_t)row*N + col], c[i][j]);
    }
  }
}

// ---------------- Split-K GEMM, 64x128 tile, 8x4 micro, double-buffered (fp32 A only) ---------------
__global__ __launch_bounds__(256) void gemm64_db_kernel(const float* __restrict__ A,
                                                        const float* __restrict__ B, int ldb,
                                                        float* __restrict__ C,
                                                        int M, int N, int K, int kchunk){
  __shared__ __align__(16) float As[2][16][68];
  __shared__ __align__(16) float Bs[2][16][132];
  int tid = threadIdx.x;
  int tx = tid & 31, ty = tid >> 5;
  int m0 = blockIdx.y * 64, n0 = blockIdx.x * 128;
  int kz = blockIdx.z * kchunk;
  const int nsteps = kchunk >> 4;
  float acc[2][4][4] = {};

  float4 ra, rb0, rb1;
  const int ar  = tid >> 2,  akc = (tid & 3) * 4;
  const int bkk = tid >> 5,  bnc = (tid & 31) * 4;

  {
    int k0 = kz;
    ra  = *(const float4*)(A + (size_t)(m0 + ar)*K + k0 + akc);
    rb0 = *(const float4*)(B + (size_t)(k0 + bkk    )*ldb + n0 + bnc);
    rb1 = *(const float4*)(B + (size_t)(k0 + bkk + 8)*ldb + n0 + bnc);
  }

  for (int s = 0; s < nsteps; ++s){
    const int buf = s & 1;
    As[buf][akc    ][ar] = ra.x;
    As[buf][akc + 1][ar] = ra.y;
    As[buf][akc + 2][ar] = ra.z;
    As[buf][akc + 3][ar] = ra.w;
    *(float4*)&Bs[buf][bkk    ][bnc] = rb0;
    *(float4*)&Bs[buf][bkk + 8][bnc] = rb1;
    __syncthreads();
    if (s + 1 < nsteps){
      int k0 = kz + (s+1)*16;
      ra  = *(const float4*)(A + (size_t)(m0 + ar)*K + k0 + akc);
      rb0 = *(const float4*)(B + (size_t)(k0 + bkk    )*ldb + n0 + bnc);
      rb1 = *(const float4*)(B + (size_t)(k0 + bkk + 8)*ldb + n0 + bnc);
    }
    #pragma unroll
    for (int kk = 0; kk < 16; ++kk){
      float4 a0 = *(const float4*)&As[buf][kk][ty*4];
      float4 a1 = *(const float4*)&As[buf][kk][32 + ty*4];
      float4 b  = *(const float4*)&Bs[buf][kk][tx*4];
      float ar2[2][4] = {{a0.x,a0.y,a0.z,a0.w},{a1.x,a1.y,a1.z,a1.w}};
      float br2[4]    = {b.x,b.y,b.z,b.w};
      #pragma unroll
      for (int q = 0; q < 2; ++q)
        #pragma unroll
        for (int i = 0; i < 4; ++i)
          #pragma unroll
          for (int j = 0; j < 4; ++j)
            acc[q][i][j] += ar2[q][i] * br2[j];
    }
  }
  #pragma unroll
  for (int q = 0; q < 2; ++q)
    #pragma unroll
    for (int i = 0; i < 4; ++i){
      int row = m0 + q*32 + ty*4 + i;
      #pragma unroll
      for (int j = 0; j < 4; ++j){
        int col = n0 + tx*4 + j;
        atomicAdd(&C[(size_t)row*N + col], acc[q][i][j]);
      }
    }
}

// ---------------- out-GEMM via bf16 MFMA with hi/lo-split B (near-fp32 exact) -----------------------
// C[1024][2048] = A(bf16)[1024][2048] @ B(fp32)[2048][2048]  (proven round-3 structure)
__global__ __launch_bounds__(256) void gemm_mfma_out_kernel(const bf16* __restrict__ A,
                                                            const float* __restrict__ B,
                                                            float* __restrict__ C){
  const int n0 = blockIdx.x * 128;
  const int m0 = blockIdx.y * 64;
  const int tid = threadIdx.x;
  const int wid = tid >> 6, lane = tid & 63;
  const int l15 = lane & 15, lg = lane >> 4;
  const int wc = wid * 32;
  __shared__ __align__(16) float Bs[2][32][133];

  const int skk = tid >> 3, sc4 = (tid & 7) * 4;

  f32x4 acc[4][2];
  #pragma unroll
  for (int m = 0; m < 4; ++m)
    #pragma unroll
    for (int nf = 0; nf < 2; ++nf)
      acc[m][nf] = (f32x4){0.f,0.f,0.f,0.f};

  float4 rb[4];
  int4   rafr[4];
  {
    const int k0 = 0;
    #pragma unroll
    for (int i = 0; i < 4; ++i)
      rb[i] = *(const float4*)(B + (size_t)(k0 + skk)*DIM + n0 + sc4 + i*32);
    #pragma unroll
    for (int m = 0; m < 4; ++m)
      rafr[m] = *(const int4*)(A + (size_t)(m0 + m*16 + l15)*DIM + k0 + lg*8);
  }

  for (int s = 0; s < 64; ++s){
    const int buf = s & 1;
    #pragma unroll
    for (int i = 0; i < 4; ++i)
      *(float4*)&Bs[buf][skk][sc4 + i*32] = rb[i];
    int4 afr[4];
    #pragma unroll
    for (int m = 0; m < 4; ++m) afr[m] = rafr[m];
    __syncthreads();
    if (s + 1 < 64){
      const int k0 = (s+1)*32;
      #pragma unroll
      for (int i = 0; i < 4; ++i)
        rb[i] = *(const float4*)(B + (size_t)(k0 + skk)*DIM + n0 + sc4 + i*32);
      #pragma unroll
      for (int m = 0; m < 4; ++m)
        rafr[m] = *(const int4*)(A + (size_t)(m0 + m*16 + l15)*DIM + k0 + lg*8);
    }
    #pragma unroll
    for (int nf = 0; nf < 2; ++nf){
      const int col = wc + nf*16 + l15;
      float bv[8];
      #pragma unroll
      for (int j = 0; j < 8; ++j) bv[j] = Bs[buf][lg*8 + j][col];
      bf16x8 bh, bl;
      #pragma unroll
      for (int j = 0; j < 8; ++j){
        unsigned short h = f2bf(bv[j]);
        float hf = bfbits2f(h);
        unsigned short l = f2bf(bv[j] - hf);
        bh[j] = (short)h;
        bl[j] = (short)l;
      }
      #pragma unroll
      for (int m = 0; m < 4; ++m){
        union { int4 i; bf16x8 v; } ua; ua.i = afr[m];
        acc[m][nf] = __builtin_amdgcn_mfma_f32_16x16x32_bf16(ua.v, bh, acc[m][nf], 0, 0, 0);
        acc[m][nf] = __builtin_amdgcn_mfma_f32_16x16x32_bf16(ua.v, bl, acc[m][nf], 0, 0, 0);
      }
    }
  }
  #pragma unroll
  for (int m = 0; m < 4; ++m)
    #pragma unroll
    for (int nf = 0; nf < 2; ++nf){
      const int col = n0 + wc + nf*16 + l15;
      #pragma unroll
      for (int r = 0; r < 4; ++r){
        const int row = m0 + m*16 + lg*4 + r;
        C[(size_t)row*DIM + col] = acc[m][nf][r];
      }
    }
}

// ---------------- q-GEMM via bf16 MFMA with hi/lo split on BOTH operands (3-term) -------------------
// C[1024][2048] = A(fp32 xn)[1024][2048] @ B(fp32 W_qkv[:,0:2048], ldb=2560)
// A = Ah+Al, B = Bh+Bl (bf16 RNE splits, residual ~2^-18 rel each). Terms kept:
// AhBh + AlBh + AhBl; dropped AlBl ~2^-18|A||B| -> q error ~1e-5 class (selection-safe;
// selections already survive split-K-vs-JAX ordering deltas of similar class).
// Same tile/wave geometry as gemm_mfma_out_kernel. Direct stores, no atomics.
__global__ __launch_bounds__(256) void gemm_mfma_q_kernel(const float* __restrict__ A,
                                                          const float* __restrict__ B,
                                                          float* __restrict__ C){
  const int n0 = blockIdx.x * 128;
  const int m0 = blockIdx.y * 64;
  const int tid = threadIdx.x;
  const int wid = tid >> 6, lane = tid & 63;
  const int l15 = lane & 15, lg = lane >> 4;
  const int wc = wid * 32;
  __shared__ __align__(16) float Bs[2][32][133];

  const int skk = tid >> 3, sc4 = (tid & 7) * 4;

  f32x4 acc[4][2];
  #pragma unroll
  for (int m = 0; m < 4; ++m)
    #pragma unroll
    for (int nf = 0; nf < 2; ++nf)
      acc[m][nf] = (f32x4){0.f,0.f,0.f,0.f};

  float4 rb[4];
  float4 raf[4][2];     // per m-frag: 8 fp32 of A (two float4)
  {
    const int k0 = 0;
    #pragma unroll
    for (int i = 0; i < 4; ++i)
      rb[i] = *(const float4*)(B + (size_t)(k0 + skk)*2560 + n0 + sc4 + i*32);
    #pragma unroll
    for (int m = 0; m < 4; ++m){
      const float* ap = A + (size_t)(m0 + m*16 + l15)*DIM + k0 + lg*8;
      raf[m][0] = *(const float4*)ap;
      raf[m][1] = *(const float4*)(ap + 4);
    }
  }

  for (int s = 0; s < 64; ++s){
    const int buf = s & 1;
    #pragma unroll
    for (int i = 0; i < 4; ++i)
      *(float4*)&Bs[buf][skk][sc4 + i*32] = rb[i];
    // convert current A frags to hi/lo bf16x8
    bf16x8 ah[4], al[4];
    #pragma unroll
    for (int m = 0; m < 4; ++m){
      float av[8];
      *(float4*)&av[0] = raf[m][0];
      *(float4*)&av[4] = raf[m][1];
      #pragma unroll
      for (int j = 0; j < 8; ++j){
        unsigned short h = f2bf(av[j]);
        float hf = bfbits2f(h);
        unsigned short l = f2bf(av[j] - hf);
        ah[m][j] = (short)h;
        al[m][j] = (short)l;
      }
    }
    __syncthreads();
    if (s + 1 < 64){
      const int k0 = (s+1)*32;
      #pragma unroll
      for (int i = 0; i < 4; ++i)
        rb[i] = *(const float4*)(B + (size_t)(k0 + skk)*2560 + n0 + sc4 + i*32);
      #pragma unroll
      for (int m = 0; m < 4; ++m){
        const float* ap = A + (size_t)(m0 + m*16 + l15)*DIM + k0 + lg*8;
        raf[m][0] = *(const float4*)ap;
        raf[m][1] = *(const float4*)(ap + 4);
      }
    }
    #pragma unroll
    for (int nf = 0; nf < 2; ++nf){
      const int col = wc + nf*16 + l15;
      float bv[8];
      #pragma unroll
      for (int j = 0; j < 8; ++j) bv[j] = Bs[buf][lg*8 + j][col];
      bf16x8 bh, bl;
      #pragma unroll
      for (int j = 0; j < 8; ++j){
        unsigned short h = f2bf(bv[j]);
        float hf = bfbits2f(h);
        unsigned short l = f2bf(bv[j] - hf);
        bh[j] = (short)h;
        bl[j] = (short)l;
      }
      #pragma unroll
      for (int m = 0; m < 4; ++m){
        acc[m][nf] = __builtin_amdgcn_mfma_f32_16x16x32_bf16(ah[m], bh, acc[m][nf], 0, 0, 0);
        acc[m][nf] = __builtin_amdgcn_mfma_f32_16x16x32_bf16(al[m], bh, acc[m][nf], 0, 0, 0);
        acc[m][nf] = __builtin_amdgcn_mfma_f32_16x16x32_bf16(ah[m], bl, acc[m][nf], 0, 0, 0);
      }
    }
  }
  #pragma unroll
  for (int m = 0; m < 4; ++m)
    #pragma unroll
    for (int nf = 0; nf < 2; ++nf){
      const int col = n0 + wc + nf*16 + l15;
      #pragma unroll
      for (int r = 0; r < 4; ++r){
        const int row = m0 + m*16 + lg*4 + r;
        C[(size_t)row*DIM + col] = acc[m][nf][r];
      }
    }
}

// ---------------- RoPE: q fp32 [n][2048], kv fp32 [n][512] -> qr bf16 [n][2048], kr bf16 [n][256] ----
__global__ __launch_bounds__(256) void rope_kernel(const float* __restrict__ q,
    const float* __restrict__ kv, bf16* __restrict__ qr, bf16* __restrict__ kr){
  int n = blockIdx.x, tid = threadIdx.x;
  const float* qrow = q + (size_t)n*DIM;
  bf16* qrrow = qr + (size_t)n*DIM;
  #pragma unroll
  for (int i = 0; i < 4; ++i){
    int p = tid + i*256;
    int hd = p >> 6, ii = p & 63;
    float inv = powf(10000.f, -(float)ii/64.f);
    float ang = (float)n * inv;
    float cs = cosf(ang), sn = sinf(ang);
    float x1 = qrow[hd*DH + 2*ii], x2 = qrow[hd*DH + 2*ii + 1];
    qrrow[hd*DH + 2*ii]     = __float2bfloat16(x1*cs - x2*sn);
    qrrow[hd*DH + 2*ii + 1] = __float2bfloat16(x1*sn + x2*cs);
  }
  if (tid < 128){
    int h = tid >> 6, ii = tid & 63;
    float inv = powf(10000.f, -(float)ii/64.f);
    float ang = (float)n * inv;
    float cs = cosf(ang), sn = sinf(ang);
    const float* kvrow = kv + (size_t)n*512;
    float x1 = kvrow[h*DH + 2*ii], x2 = kvrow[h*DH + 2*ii + 1];
    bf16* krrow = kr + (size_t)n*256;
    krrow[h*DH + 2*ii]     = __float2bfloat16(x1*cs - x2*sn);
    krrow[h*DH + 2*ii + 1] = __float2bfloat16(x1*sn + x2*cs);
  }
}

// ---------------- Build compression-MLP input f [128][CDIM] (k: voff=0, v: voff=256) ----------------
__global__ __launch_bounds__(256) void build_f_kernel(const float* __restrict__ kv, int voff,
    const float* __restrict__ pos, float* __restrict__ f){
  int bw = blockIdx.x;           // h*NWIN + w
  int h = bw >> 6, w = bw & 63;
  int tid = threadIdx.x;
  for (int idx = tid; idx < CMP_BLK*DH; idx += 256){
    int j = idx >> 7, d = idx & 127;
    int t = w*16 + j - 16;       // padded window index
    float kvv = (t >= 0) ? kv[(size_t)t*512 + voff + h*DH + d] : 0.f;
    f[(size_t)bw*CDIM + idx] = kvv + pos[(h*CMP_BLK + j)*DH + d];
  }
}

// ---------------- Assemble ck/cv [KVH][NCMP][DH]; MLP second bias folded here ----------------
__global__ __launch_bounds__(256) void assemble_kernel(const float* __restrict__ ckb,
    const float* __restrict__ cvb, const float* __restrict__ mem_kv,
    const float* __restrict__ bk2, const float* __restrict__ bv2,
    float* __restrict__ ck, float* __restrict__ cv){
  int j = blockIdx.x;            // 0..64
  int tid = threadIdx.x;         // 256 = KVH*DH
  int h = tid >> 7, d = tid & 127;
  float kvx, vvx;
  if (j == 0){
    kvx = mem_kv[(0*KVH + h)*DH + d];
    vvx = mem_kv[(1*KVH + h)*DH + d];
  } else {
    kvx = ckb[((size_t)h*NWIN + (j-1))*DH + d] + bk2[d];
    vvx = cvb[((size_t)h*NWIN + (j-1))*DH + d] + bv2[d];
  }
  ck[((size_t)h*NCMP + j)*DH + d] = kvx;
  cv[((size_t)h*NCMP + j)*DH + d] = vvx;
}

// ---------------- Compressed attention (pre-rope q, fp32) + importance + top-4 selection ----------------
__global__ __launch_bounds__(256) void cmp_attn_kernel(const float* __restrict__ q,
    const float* __restrict__ ck, const float* __restrict__ cv,
    bf16* __restrict__ cmp_o, int* __restrict__ sel){
  int bx = blockIdx.x;
  int h = bx >> 10, n = bx & 1023;
  int tid = threadIdx.x;
  __shared__ float cks[NCMP*129];
  __shared__ float qs[GQ*DH];
  __shared__ float sims[GQ*66];
  __shared__ float red[GQ*32];
  __shared__ float impb[NFINE];
  for (int idx = tid; idx < NCMP*DH; idx += 256){
    int j = idx >> 7, d = idx & 127;
    cks[j*129 + d] = ck[((size_t)h*NCMP + j)*DH + d];
  }
  for (int idx = tid; idx < GQ*DH; idx += 256)
    qs[idx] = q[(size_t)n*DIM + h*(GQ*DH) + idx];
  __syncthreads();
  for (int p = tid; p < GQ*NCMP; p += 256){
    int g = p / NCMP, j = p % NCMP;
    float acc = 0.f;
    const float* qp = &qs[g*DH];
    const float* kp = &cks[j*129];
    #pragma unroll 4
    for (int d = 0; d < DH; ++d) acc += qp[d]*kp[d];
    sims[g*66 + j] = acc * SCALE;
  }
  __syncthreads();
  if (tid < NFINE){
    float s = 0.f;
    for (int g = 0; g < GQ; ++g)
      #pragma unroll
      for (int c = 0; c < 4; ++c)
        s += sims[g*66 + 1 + tid*4 + c];
    impb[tid] = s;
  }
  __syncthreads();
  if (tid == 0){
    int own = n >> 6;
    impb[own] = -1e30f;
    int selbuf[5];
    #pragma unroll
    for (int r = 0; r < 4; ++r){
      float best = -1e38f; int bi = 0;
      for (int f = 0; f < NFINE; ++f)
        if (impb[f] > best){ best = impb[f]; bi = f; }   // strict > : lowest index on ties
      selbuf[r] = bi; impb[bi] = -1e38f;
    }
    selbuf[4] = own;
    for (int r = 0; r < 5; ++r) sel[(size_t)(h*N_TOK + n)*8 + r] = selbuf[r];
  }
  int g = tid >> 5, lane = tid & 31;
  float m = -1e38f;
  for (int j = lane; j < NCMP; j += 32) m = fmaxf(m, sims[g*66 + j]);
  red[g*32 + lane] = m; __syncthreads();
  for (int st = 16; st > 0; st >>= 1){ if (lane < st) red[g*32+lane] = fmaxf(red[g*32+lane], red[g*32+lane+st]); __syncthreads(); }
  float gm = red[g*32]; __syncthreads();
  float ps = 0.f;
  for (int j = lane; j < NCMP; j += 32){ float e = expf(sims[g*66+j] - gm); sims[g*66+j] = e; ps += e; }
  red[g*32+lane] = ps; __syncthreads();
  for (int st = 16; st > 0; st >>= 1){ if (lane < st) red[g*32+lane] += red[g*32+lane+st]; __syncthreads(); }
  float inv = 1.f / red[g*32]; __syncthreads();
  for (int j = lane; j < NCMP; j += 32) sims[g*66+j] *= inv;
  __syncthreads();
  for (int p = tid; p < GQ*DH; p += 256){
    int gg = p >> 7, d = p & 127;
    float acc = 0.f;
    const float* cvp = cv + (size_t)h*NCMP*DH + d;
    for (int j = 0; j < NCMP; ++j) acc += sims[gg*66 + j] * cvp[j*DH];
    cmp_o[(size_t)n*DIM + (h*GQ + gg)*DH + d] = __float2bfloat16(acc);
  }
}

// ---------------- Fine (selected-block) attention: roped q/k (bf16), raw v (fp32 strided) ------------
__global__ __launch_bounds__(256) void fine_attn_kernel(const bf16* __restrict__ qr,
    const bf16* __restrict__ kr, const float* __restrict__ kv,
    const int* __restrict__ sel, bf16* __restrict__ fine_o){
  int bx = blockIdx.x;
  int h = bx >> 10, n = bx & 1023;
  int tid = threadIdx.x;
  __shared__ float kt[SEL_BLK*129];
  __shared__ float qs[GQ*DH];
  __shared__ float sims[GQ*321];
  __shared__ float red[GQ*32];
  int sel5[5];
  #pragma unroll
  for (int r = 0; r < 5; ++r){
    int b = sel[(size_t)(h*N_TOK + n)*8 + r];
    sel5[r] = (b < 0) ? 0 : (b > 15 ? 15 : b);
  }
  for (int idx = tid; idx < GQ*DH; idx += 256)
    qs[idx] = b2f(qr[(size_t)n*DIM + h*(GQ*DH) + idx]);
  for (int tile = 0; tile < 5; ++tile){
    int blk = sel5[tile];
    __syncthreads();
    for (int idx = tid; idx < SEL_BLK*DH; idx += 256){
      int tl = idx >> 7, d = idx & 127;
      kt[tl*129 + d] = b2f(kr[(size_t)(blk*SEL_BLK + tl)*256 + h*DH + d]);
    }
    __syncthreads();
    for (int p = tid; p < GQ*SEL_BLK; p += 256){
      int g = p >> 6, t = p & 63;
      float acc = 0.f;
      const float* qp = &qs[g*DH];
      const float* kp = &kt[t*129];
      #pragma unroll 4
      for (int d = 0; d < DH; ++d) acc += qp[d]*kp[d];
      sims[g*321 + tile*SEL_BLK + t] = acc * SCALE;
    }
  }
  __syncthreads();
  int g = tid >> 5, lane = tid & 31;
  float m = -1e38f;
  for (int t = lane; t < T_TOT; t += 32) m = fmaxf(m, sims[g*321 + t]);
  red[g*32+lane] = m; __syncthreads();
  for (int st = 16; st > 0; st >>= 1){ if (lane < st) red[g*32+lane] = fmaxf(red[g*32+lane], red[g*32+lane+st]); __syncthreads(); }
  float gm = red[g*32]; __syncthreads();
  float ps = 0.f;
  for (int t = lane; t < T_TOT; t += 32){ float e = expf(sims[g*321+t] - gm); sims[g*321+t] = e; ps += e; }
  red[g*32+lane] = ps; __syncthreads();
  for (int st = 16; st > 0; st >>= 1){ if (lane < st) red[g*32+lane] += red[g*32+lane+st]; __syncthreads(); }
  float inv = 1.f / red[g*32]; __syncthreads();
  for (int t = lane; t < T_TOT; t += 32) sims[g*321+t] *= inv;
  float acc[4] = {0.f,0.f,0.f,0.f};
  for (int tile = 0; tile < 5; ++tile){
    int blk = sel5[tile];
    __syncthreads();
    for (int idx = tid; idx < SEL_BLK*DH; idx += 256){
      int tl = idx >> 7, d = idx & 127;
      kt[tl*129 + d] = kv[(size_t)(blk*SEL_BLK + tl)*512 + 256 + h*DH + d];
    }
    __syncthreads();
    #pragma unroll
    for (int i = 0; i < 4; ++i){
      int p = tid + i*256;
      int gg = p >> 7, d = p & 127;
      float a = acc[i];
      const float* sp = &sims[gg*321 + tile*SEL_BLK];
      const float* vp = &kt[d];
      for (int t = 0; t < SEL_BLK; ++t) a += sp[t]*vp[t*129];
      acc[i] = a;
    }
  }
  #pragma unroll
  for (int i = 0; i < 4; ++i){
    int p = tid + i*256;
    int gg = p >> 7, d = p & 127;
    fine_o[(size_t)n*DIM + (h*GQ + gg)*DH + d] = __float2bfloat16(acc[i]);
  }
}

// ---------------- Sliding-window attention, flash-style online softmax --------------------------
__global__ __launch_bounds__(256) void slide_attn_kernel(const bf16* __restrict__ qr,
    const bf16* __restrict__ kr, const float* __restrict__ kv,
    bf16* __restrict__ slide_o){
  int hq = blockIdx.y;          // 16 heads
  int qt = blockIdx.x;          // 32 query tiles of 32
  int h = hq >> 3;
  int n0 = qt * 32;
  int tid = threadIdx.x;
  __shared__ float qT[128*36];   // [d][qi], pad 36
  __shared__ float kvb[128*68];  // K^T [d][t] pad 68 (QK) | V [t][128] (PV)
  __shared__ float stT[64*36];   // [t][qi] exp'd probs, pad 36

  const int ty  = tid >> 5;
  const int tx  = tid & 31;
  const int qi0 = ty << 2;

  for (int c = tid; c < 512; c += 256){
    int qi = c & 31, d0 = (c >> 5) << 3;
    int4 w = *(const int4*)(qr + (size_t)(n0+qi)*DIM + hq*DH + d0);
    float* dst = &qT[(size_t)d0*36 + qi];
    unsigned int wv[4] = {(unsigned)w.x,(unsigned)w.y,(unsigned)w.z,(unsigned)w.w};
    #pragma unroll
    for (int m = 0; m < 4; ++m){
      dst[(2*m  )*36] = bfbits2f(wv[m] & 0xffffu);
      dst[(2*m+1)*36] = bfbits2f(wv[m] >> 16);
    }
  }

  float acc[4][4] = {};
  float mrow[4] = {-1e30f,-1e30f,-1e30f,-1e30f};
  float lrow[4] = {0.f,0.f,0.f,0.f};
  float arow[4];
  const int kstart = n0 - 128;

  for (int tile = 0; tile < 5; ++tile){
    const int kbase = kstart + tile*64;
    __syncthreads();
    for (int c = tid; c < 1024; c += 256){
      int t = c & 63, d0 = (c >> 6) << 3;
      int kg = kbase + t;
      int kgc = min(max(kg, 0), N_TOK-1);
      int4 w = *(const int4*)(kr + (size_t)kgc*256 + h*DH + d0);
      float* dst = &kvb[(size_t)d0*68 + t];
      unsigned int wv[4] = {(unsigned)w.x,(unsigned)w.y,(unsigned)w.z,(unsigned)w.w};
      #pragma unroll
      for (int m = 0; m < 4; ++m){
        dst[(2*m  )*68] = bfbits2f(wv[m] & 0xffffu);
        dst[(2*m+1)*68] = bfbits2f(wv[m] >> 16);
      }
    }
    __syncthreads();
    float c0[8] = {};
    {
      const float* aP = qT + qi0;
      const float* bP = kvb + (tx << 1);
      #pragma unroll 4
      for (int d = 0; d < 128; ++d){
        float4 a = *(const float4*)(aP + d*36);
        float2 b = *(const float2*)(bP + d*68);
        c0[0] += a.x*b.x; c0[1] += a.x*b.y;
        c0[2] += a.y*b.x; c0[3] += a.y*b.y;
        c0[4] += a.z*b.x; c0[5] += a.z*b.y;
        c0[6] += a.w*b.x; c0[7] += a.w*b.y;
      }
    }
    const int kg0 = kbase + (tx << 1);
    #pragma unroll
    for (int i = 0; i < 4; ++i){
      int qg = n0 + qi0 + i;
      int d0 = qg - kg0, d1 = d0 - 1;
      bool v0 = (kg0   >= 0) && (kg0   < N_TOK) && (d0 <= 128) && (d0 >= -128);
      bool v1 = (kg0+1 >= 0) && (kg0+1 < N_TOK) && (d1 <= 128) && (d1 >= -128);
      float s0 = v0 ? c0[i*2  ]*SCALE : -1e30f;
      float s1 = v1 ? c0[i*2+1]*SCALE : -1e30f;
      float mi = fmaxf(s0, s1);
      #pragma unroll
      for (int off = 1; off < 32; off <<= 1) mi = fmaxf(mi, __shfl_xor(mi, off));
      float mold = mrow[i];
      float mnew = fmaxf(fmaxf(mold, mi), -1e20f);
      arow[i] = expf(mold - mnew);
      mrow[i] = mnew;
      float e0 = expf(s0 - mnew);
      float e1 = expf(s1 - mnew);
      float ps = e0 + e1;
      #pragma unroll
      for (int off = 1; off < 32; off <<= 1) ps += __shfl_xor(ps, off);
      lrow[i] = lrow[i]*arow[i] + ps;
      stT[(size_t)(2*tx  )*36 + qi0 + i] = e0;
      stT[(size_t)(2*tx+1)*36 + qi0 + i] = e1;
    }
    __syncthreads();
    for (int c = tid; c < 2048; c += 256){
      int t = c >> 5, d0 = (c & 31) << 2;
      int kg = kbase + t;
      int kgc = min(max(kg, 0), N_TOK-1);
      float4 v = *(const float4*)(kv + (size_t)kgc*512 + 256 + h*DH + d0);
      *(float4*)&kvb[(size_t)t*128 + d0] = v;
    }
    __syncthreads();
    #pragma unroll
    for (int i = 0; i < 4; ++i){
      float ar = arow[i];
      acc[i][0] *= ar; acc[i][1] *= ar; acc[i][2] *= ar; acc[i][3] *= ar;
    }
    {
      const float* pP = stT + qi0;
      const float* vP = kvb + (tx << 2);
      #pragma unroll 4
      for (int t = 0; t < 64; ++t){
        float4 p = *(const float4*)(pP + t*36);
        float4 v = *(const float4*)(vP + t*128);
        acc[0][0] += p.x*v.x; acc[0][1] += p.x*v.y; acc[0][2] += p.x*v.z; acc[0][3] += p.x*v.w;
        acc[1][0] += p.y*v.x; acc[1][1] += p.y*v.y; acc[1][2] += p.y*v.z; acc[1][3] += p.y*v.w;
        acc[2][0] += p.z*v.x; acc[2][1] += p.z*v.y; acc[2][2] += p.z*v.z; acc[2][3] += p.z*v.w;
        acc[3][0] += p.w*v.x; acc[3][1] += p.w*v.y; acc[3][2] += p.w*v.z; acc[3][3] += p.w*v.w;
      }
    }
  }
  #pragma unroll
  for (int i = 0; i < 4; ++i){
    int row = n0 + qi0 + i;
    float inv = 1.f / lrow[i];
    bf16 o[4];
    o[0] = __float2bfloat16(acc[i][0]*inv);
    o[1] = __float2bfloat16(acc[i][1]*inv);
    o[2] = __float2bfloat16(acc[i][2]*inv);
    o[3] = __float2bfloat16(acc[i][3]*inv);
    *(ushort4*)(slide_o + (size_t)row*DIM + hq*DH + (tx << 2)) = *(const ushort4*)o;
  }
}

// ---------------- Gated combine; gate bias+sigmoid folded here -> ocomb bf16 [n][2048] --------------
__global__ __launch_bounds__(256) void combine_kernel(const bf16* __restrict__ cmp_o,
    const bf16* __restrict__ fine_o, const bf16* __restrict__ slide_o,
    const float* __restrict__ graw, const float* __restrict__ bg,
    bf16* __restrict__ ocomb){
  int n = blockIdx.x, tid = threadIdx.x;
  #pragma unroll
  for (int i = 0; i < 8; ++i){
    int c = tid + i*256;
    int hq = c >> 7;
    float g0 = 1.f/(1.f + expf(-(graw[(size_t)n*48 + hq*3 + 0] + bg[hq*3 + 0])));
    float g1 = 1.f/(1.f + expf(-(graw[(size_t)n*48 + hq*3 + 1] + bg[hq*3 + 1])));
    float g2 = 1.f/(1.f + expf(-(graw[(size_t)n*48 + hq*3 + 2] + bg[hq*3 + 2])));
    size_t idx = (size_t)n*DIM + c;
    ocomb[idx] = __float2bfloat16(b2f(cmp_o[idx])*g0 + b2f(fine_o[idx])*g1 + b2f(slide_o[idx])*g2);
  }
}

extern "C" void kernel_launch(void* const* d_in, const int* in_sizes, int n_in,
                              void* d_out, int out_size, void* d_ws, size_t ws_size,
                              hipStream_t stream)
{
  const float* x      = (const float*)d_in[0];
  const float* g_norm = (const float*)d_in[1];
  const float* W_qkv  = (const float*)d_in[2];
  const float* k_pos  = (const float*)d_in[3];
  const float* v_pos  = (const float*)d_in[4];
  const float* mem_kv = (const float*)d_in[5];
  const float* Wk1    = (const float*)d_in[6];
  const float* bk1    = (const float*)d_in[7];
  const float* Wk2    = (const float*)d_in[8];
  const float* bk2    = (const float*)d_in[9];
  const float* Wv1    = (const float*)d_in[10];
  const float* bv1    = (const float*)d_in[11];
  const float* Wv2    = (const float*)d_in[12];
  const float* bv2    = (const float*)d_in[13];
  const float* Wg     = (const float*)d_in[14];
  const float* bg     = (const float*)d_in[15];
  const float* W_out  = (const float*)d_in[16];
  float* out = (float*)d_out;
  (void)ws_size; (void)in_sizes; (void)n_in; (void)out_size;

  // ---- Workspace layout (bytes), total ~23.6 MB, aggressive region reuse ----
  char* base = (char*)d_ws;
  float* q     = (float*)(base + 0);                 // 8 MB [n][2048] fp32, live -> cmp_attn
  float* xn    = (float*)(base + 8388608);           // 8 MB fp32, live -> kv GEMM
  bf16*  qr    = (bf16*) (base + 8388608);           // 4 MB (over xn, after xn dead)
  bf16*  kr    = (bf16*) (base + 12582912);          // 0.5 MB
  bf16*  ocomb = (bf16*) (base + 8388608);           // 4 MB (over qr, after slide)
  float* kv    = (float*)(base + 16777216);          // 2 MB [n][512] fp32
  float* fbuf  = (float*)(base + 18874368);          // 2 MB fk / fv
  float* hbuf  = (float*)(base + 20971520);          // 2 MB hk / hv (raw, bias folded downstream)
  bf16*  cmp_o = (bf16*) (base + 18874368);          // 4 MB (over fbuf+hbuf, after MLPs)
  float* ckb   = (float*)(base + 23068672);          // 64 KB (raw)
  float* cvb   = (float*)(base + 23134208);          // 64 KB (raw)
  float* ck    = (float*)(base + 23199744);          // 65 KB
  float* cv    = (float*)(base + 23266304);          // 65 KB
  float* gates = (float*)(base + 23332864);          // 192 KB (raw, sigmoid folded in combine)
  int*   sel   = (int*)  (base + 23529472);          // 64 KB   (end: 23,595,008 B)
  bf16*  fine_o  = (bf16*)(base + 0);                // 4 MB (over q, after cmp_attn)
  bf16*  slide_o = (bf16*)(base + 4194304);          // 4 MB (over q upper half)

  // Zero split-K accumulation targets (stream-ordered; graph-capture legal)
  // (q no longer needs zeroing: MFMA q-GEMM does direct stores)
  hipMemsetAsync(kv,    0, (size_t)N_TOK*512*4,  stream);
  hipMemsetAsync(gates, 0, (size_t)N_TOK*48*4,   stream);
  hipMemsetAsync(ckb,   0, (size_t)KVH*NWIN*DH*4, stream);
  hipMemsetAsync(cvb,   0, (size_t)KVH*NWIN*DH*4, stream);

  rmsnorm_kernel<<<N_TOK, 256, 0, stream>>>(x, g_norm, xn);
  // gates_raw = xn @ Wg            [1024 x 48],  small -> old 64x64 kernel
  gemm_splitk_kernel<<<dim3(1, 16, 8), 256, 0, stream>>>(xn, 0, nullptr, Wg, 48, gates, N_TOK, 48, DIM, 256);
  // q = xn @ W_qkv[:, 0:2048] via 3-term hi/lo MFMA (direct stores, ~1e-5-class residual)
  gemm_mfma_q_kernel<<<dim3(16, 16), 256, 0, stream>>>(xn, W_qkv, q);
  // kv = xn @ W_qkv[:, 2048:2560]  [1024 x 512], 64x128 dbuf, kchunk=256 (exact fp32 path)
  gemm64_db_kernel<<<dim3(4, 16, 8), 256, 0, stream>>>(xn, W_qkv + 2048, 2560, kv, N_TOK, 512, DIM, 256);
  // qr, kr (bf16) — xn now dead
  rope_kernel<<<N_TOK, 256, 0, stream>>>(q, kv, qr, kr);
  // compression MLPs (fp32, selection-critical via ck). relu(.+bk1) folded into MLP2 A-load; bk2 into assemble.
  build_f_kernel<<<KVH*NWIN, 256, 0, stream>>>(kv, 0, k_pos, fbuf);
  hipMemsetAsync(hbuf, 0, (size_t)KVH*NWIN*CDIM*4, stream);
  gemm64_db_kernel<<<dim3(32, 2, 8), 256, 0, stream>>>(fbuf, Wk1, CDIM, hbuf, KVH*NWIN, CDIM, CDIM, 512);
  gemm_splitk_kernel<<<dim3(2, 2, 32),  256, 0, stream>>>(hbuf, 0, bk1,     Wk2, DH,   ckb,  KVH*NWIN, DH,   CDIM, 128);
  build_f_kernel<<<KVH*NWIN, 256, 0, stream>>>(kv, 256, v_pos, fbuf);
  hipMemsetAsync(hbuf, 0, (size_t)KVH*NWIN*CDIM*4, stream);
  gemm64_db_kernel<<<dim3(32, 2, 8), 256, 0, stream>>>(fbuf, Wv1, CDIM, hbuf, KVH*NWIN, CDIM, CDIM, 512);
  gemm_splitk_kernel<<<dim3(2, 2, 32),  256, 0, stream>>>(hbuf, 0, bv1,     Wv2, DH,   cvb,  KVH*NWIN, DH,   CDIM, 128);
  assemble_kernel<<<NCMP, 256, 0, stream>>>(ckb, cvb, mem_kv, bk2, bv2, ck, cv);
  // compressed attention + selection (fbuf/hbuf dead -> cmp_o)
  cmp_attn_kernel<<<KVH*N_TOK, 256, 0, stream>>>(q, ck, cv, cmp_o, sel);
  // fine attention (q dead -> fine_o over q region)
  fine_attn_kernel<<<KVH*N_TOK, 256, 0, stream>>>(qr, kr, kv, sel, fine_o);
  // sliding attention (-> slide_o over q upper half)
  slide_attn_kernel<<<dim3(32, 16), 256, 0, stream>>>(qr, kr, kv, slide_o);
  // combine (qr dead -> ocomb over qr); sigmoid(graw+bg) folded here
  combine_kernel<<<N_TOK, 256, 0, stream>>>(cmp_o, fine_o, slide_o, gates, bg, ocomb);
  // out = ocomb @ W_out via bf16 MFMA with hi/lo-split B (near-fp32 exact, no atomics, direct stores)
  gemm_mfma_out_kernel<<<dim3(16, 16), 256, 0, stream>>>(ocomb, W_out, out);
}

// Round 6
// 1000.781 us; speedup vs baseline: 1.3578x; 1.0732x over previous
//
#include <hip/hip_runtime.h>
#include <hip/hip_bf16.h>
#include <math.h>

typedef __hip_bfloat16 bf16;
typedef __attribute__((ext_vector_type(8))) short bf16x8;
typedef __attribute__((ext_vector_type(4))) float f32x4;

#define N_TOK 1024
#define DIM 2048
#define NHEADS 16
#define KVH 2
#define DH 128
#define GQ 8
#define NWIN 64
#define CMP_BLK 32
#define NCMP 65        // MEM_KV + NWIN
#define NFINE 16
#define SEL_BLK 64
#define T_TOT 320
#define CDIM 4096      // CMP_BLK*DH
#define SCALE 0.08838834764831845f

static __device__ __forceinline__ float b2f(bf16 v){ return __bfloat162float(v); }
static __device__ __forceinline__ float bfbits2f(unsigned int u){
  union { unsigned int i; float f; } x; x.i = u << 16; return x.f;
}
// RNE float->bf16 bits (matches __float2bfloat16 for normal values)
static __device__ __forceinline__ unsigned short f2bf(float f){
  union { float f; unsigned u; } x; x.f = f;
  unsigned r = x.u + 0x7fffu + ((x.u >> 16) & 1u);
  return (unsigned short)(r >> 16);
}

// ---------------- RMSNorm: x fp32 [N,DIM] -> xn fp32 ----------------
__global__ __launch_bounds__(256) void rmsnorm_kernel(const float* __restrict__ x,
                                                      const float* __restrict__ g,
                                                      float* __restrict__ xn){
  int n = blockIdx.x, tid = threadIdx.x;
  __shared__ float red[256];
  const float* row = x + (size_t)n*DIM;
  float vals[8];
  float s = 0.f;
  #pragma unroll
  for (int i = 0; i < 8; ++i){ float v = row[tid + i*256]; vals[i] = v; s += v*v; }
  red[tid] = s; __syncthreads();
  for (int st = 128; st > 0; st >>= 1){ if (tid < st) red[tid] += red[tid+st]; __syncthreads(); }
  float scale = 1.0f / sqrtf(red[0]/(float)DIM + 1e-6f);
  #pragma unroll
  for (int i = 0; i < 8; ++i){
    int c = tid + i*256;
    xn[(size_t)n*DIM + c] = vals[i]*scale*g[c];
  }
}

// ---------------- Split-K GEMM (64x64 tile) — kept for the small shapes (gates, MLP2) --------------
__global__ __launch_bounds__(256) void gemm_splitk_kernel(const void* __restrict__ Av, int a_is_bf16,
                                                          const float* __restrict__ afold,
                                                          const float* __restrict__ B, int ldb,
                                                          float* __restrict__ C,
                                                          int M, int N, int K, int kchunk){
  __shared__ __align__(16) float As[16*68];
  __shared__ __align__(16) float Bs[16*68];
  int tid = threadIdx.x;
  int tx = tid & 15, ty = tid >> 4;
  int m0 = blockIdx.y * 64, n0 = blockIdx.x * 64;
  int kz = blockIdx.z * kchunk;
  const float* Af = (const float*)Av;
  const bf16*  Ab = (const bf16*)Av;
  float c[4][4] = {};
  for (int k0 = kz; k0 < kz + kchunk; k0 += 16){
    #pragma unroll
    for (int i = 0; i < 4; ++i){
      int idx = tid + i*256;
      int kk = idx & 15, m = idx >> 4;
      size_t aidx = (size_t)(m0+m)*K + k0 + kk;
      float av = a_is_bf16 ? b2f(Ab[aidx]) : Af[aidx];
      if (afold) av = fmaxf(av + afold[k0+kk], 0.f);
      As[kk*68 + m] = av;
    }
    #pragma unroll
    for (int i = 0; i < 4; ++i){
      int idx = tid + i*256;
      int nn = idx & 63, kk = idx >> 6;
      int col = n0 + nn;
      Bs[kk*68 + nn] = (col < N) ? B[(size_t)(k0+kk)*ldb + col] : 0.f;
    }
    __syncthreads();
    #pragma unroll
    for (int kk = 0; kk < 16; ++kk){
      float a[4], b[4];
      *(float4*)a = *(const float4*)&As[kk*68 + ty*4];
      *(float4*)b = *(const float4*)&Bs[kk*68 + tx*4];
      #pragma unroll
      for (int i = 0; i < 4; ++i)
        #pragma unroll
        for (int j = 0; j < 4; ++j)
          c[i][j] += a[i]*b[j];
    }
    __syncthreads();
  }
  #pragma unroll
  for (int i = 0; i < 4; ++i){
    int row = m0 + ty*4 + i;
    #pragma unroll
    for (int j = 0; j < 4; ++j){
      int col = n0 + tx*4 + j;
      if (col < N) atomicAdd(&C[(size_t)row*N + col], c[i][j]);
    }
  }
}

// ---------------- Split-K GEMM, 64x128 tile, 8x4 micro, double-buffered (fp32 A only) ---------------
__global__ __launch_bounds__(256) void gemm64_db_kernel(const float* __restrict__ A,
                                                        const float* __restrict__ B, int ldb,
                                                        float* __restrict__ C,
                                                        int M, int N, int K, int kchunk){
  __shared__ __align__(16) float As[2][16][68];
  __shared__ __align__(16) float Bs[2][16][132];
  int tid = threadIdx.x;
  int tx = tid & 31, ty = tid >> 5;
  int m0 = blockIdx.y * 64, n0 = blockIdx.x * 128;
  int kz = blockIdx.z * kchunk;
  const int nsteps = kchunk >> 4;
  float acc[2][4][4] = {};

  float4 ra, rb0, rb1;
  const int ar  = tid >> 2,  akc = (tid & 3) * 4;
  const int bkk = tid >> 5,  bnc = (tid & 31) * 4;

  {
    int k0 = kz;
    ra  = *(const float4*)(A + (size_t)(m0 + ar)*K + k0 + akc);
    rb0 = *(const float4*)(B + (size_t)(k0 + bkk    )*ldb + n0 + bnc);
    rb1 = *(const float4*)(B + (size_t)(k0 + bkk + 8)*ldb + n0 + bnc);
  }

  for (int s = 0; s < nsteps; ++s){
    const int buf = s & 1;
    As[buf][akc    ][ar] = ra.x;
    As[buf][akc + 1][ar] = ra.y;
    As[buf][akc + 2][ar] = ra.z;
    As[buf][akc + 3][ar] = ra.w;
    *(float4*)&Bs[buf][bkk    ][bnc] = rb0;
    *(float4*)&Bs[buf][bkk + 8][bnc] = rb1;
    __syncthreads();
    if (s + 1 < nsteps){
      int k0 = kz + (s+1)*16;
      ra  = *(const float4*)(A + (size_t)(m0 + ar)*K + k0 + akc);
      rb0 = *(const float4*)(B + (size_t)(k0 + bkk    )*ldb + n0 + bnc);
      rb1 = *(const float4*)(B + (size_t)(k0 + bkk + 8)*ldb + n0 + bnc);
    }
    #pragma unroll
    for (int kk = 0; kk < 16; ++kk){
      float4 a0 = *(const float4*)&As[buf][kk][ty*4];
      float4 a1 = *(const float4*)&As[buf][kk][32 + ty*4];
      float4 b  = *(const float4*)&Bs[buf][kk][tx*4];
      float ar2[2][4] = {{a0.x,a0.y,a0.z,a0.w},{a1.x,a1.y,a1.z,a1.w}};
      float br2[4]    = {b.x,b.y,b.z,b.w};
      #pragma unroll
      for (int q = 0; q < 2; ++q)
        #pragma unroll
        for (int i = 0; i < 4; ++i)
          #pragma unroll
          for (int j = 0; j < 4; ++j)
            acc[q][i][j] += ar2[q][i] * br2[j];
    }
  }
  #pragma unroll
  for (int q = 0; q < 2; ++q)
    #pragma unroll
    for (int i = 0; i < 4; ++i){
      int row = m0 + q*32 + ty*4 + i;
      #pragma unroll
      for (int j = 0; j < 4; ++j){
        int col = n0 + tx*4 + j;
        atomicAdd(&C[(size_t)row*N + col], acc[q][i][j]);
      }
    }
}

// ---------------- out-GEMM via bf16 MFMA with hi/lo-split B (near-fp32 exact) -----------------------
// C[1024][2048] = A(bf16)[1024][2048] @ B(fp32)[2048][2048]  (proven round-3 structure)
__global__ __launch_bounds__(256) void gemm_mfma_out_kernel(const bf16* __restrict__ A,
                                                            const float* __restrict__ B,
                                                            float* __restrict__ C){
  const int n0 = blockIdx.x * 128;
  const int m0 = blockIdx.y * 64;
  const int tid = threadIdx.x;
  const int wid = tid >> 6, lane = tid & 63;
  const int l15 = lane & 15, lg = lane >> 4;
  const int wc = wid * 32;
  __shared__ __align__(16) float Bs[2][32][133];

  const int skk = tid >> 3, sc4 = (tid & 7) * 4;

  f32x4 acc[4][2];
  #pragma unroll
  for (int m = 0; m < 4; ++m)
    #pragma unroll
    for (int nf = 0; nf < 2; ++nf)
      acc[m][nf] = (f32x4){0.f,0.f,0.f,0.f};

  float4 rb[4];
  int4   rafr[4];
  {
    const int k0 = 0;
    #pragma unroll
    for (int i = 0; i < 4; ++i)
      rb[i] = *(const float4*)(B + (size_t)(k0 + skk)*DIM + n0 + sc4 + i*32);
    #pragma unroll
    for (int m = 0; m < 4; ++m)
      rafr[m] = *(const int4*)(A + (size_t)(m0 + m*16 + l15)*DIM + k0 + lg*8);
  }

  for (int s = 0; s < 64; ++s){
    const int buf = s & 1;
    #pragma unroll
    for (int i = 0; i < 4; ++i)
      *(float4*)&Bs[buf][skk][sc4 + i*32] = rb[i];
    int4 afr[4];
    #pragma unroll
    for (int m = 0; m < 4; ++m) afr[m] = rafr[m];
    __syncthreads();
    if (s + 1 < 64){
      const int k0 = (s+1)*32;
      #pragma unroll
      for (int i = 0; i < 4; ++i)
        rb[i] = *(const float4*)(B + (size_t)(k0 + skk)*DIM + n0 + sc4 + i*32);
      #pragma unroll
      for (int m = 0; m < 4; ++m)
        rafr[m] = *(const int4*)(A + (size_t)(m0 + m*16 + l15)*DIM + k0 + lg*8);
    }
    #pragma unroll
    for (int nf = 0; nf < 2; ++nf){
      const int col = wc + nf*16 + l15;
      float bv[8];
      #pragma unroll
      for (int j = 0; j < 8; ++j) bv[j] = Bs[buf][lg*8 + j][col];
      bf16x8 bh, bl;
      #pragma unroll
      for (int j = 0; j < 8; ++j){
        unsigned short h = f2bf(bv[j]);
        float hf = bfbits2f(h);
        unsigned short l = f2bf(bv[j] - hf);
        bh[j] = (short)h;
        bl[j] = (short)l;
      }
      #pragma unroll
      for (int m = 0; m < 4; ++m){
        union { int4 i; bf16x8 v; } ua; ua.i = afr[m];
        acc[m][nf] = __builtin_amdgcn_mfma_f32_16x16x32_bf16(ua.v, bh, acc[m][nf], 0, 0, 0);
        acc[m][nf] = __builtin_amdgcn_mfma_f32_16x16x32_bf16(ua.v, bl, acc[m][nf], 0, 0, 0);
      }
    }
  }
  #pragma unroll
  for (int m = 0; m < 4; ++m)
    #pragma unroll
    for (int nf = 0; nf < 2; ++nf){
      const int col = n0 + wc + nf*16 + l15;
      #pragma unroll
      for (int r = 0; r < 4; ++r){
        const int row = m0 + m*16 + lg*4 + r;
        C[(size_t)row*DIM + col] = acc[m][nf][r];
      }
    }
}

// ---------------- q-GEMM via bf16 MFMA with hi/lo split on BOTH operands (3-term) -------------------
// (proven round-4 structure; see comment history)
__global__ __launch_bounds__(256) void gemm_mfma_q_kernel(const float* __restrict__ A,
                                                          const float* __restrict__ B,
                                                          float* __restrict__ C){
  const int n0 = blockIdx.x * 128;
  const int m0 = blockIdx.y * 64;
  const int tid = threadIdx.x;
  const int wid = tid >> 6, lane = tid & 63;
  const int l15 = lane & 15, lg = lane >> 4;
  const int wc = wid * 32;
  __shared__ __align__(16) float Bs[2][32][133];

  const int skk = tid >> 3, sc4 = (tid & 7) * 4;

  f32x4 acc[4][2];
  #pragma unroll
  for (int m = 0; m < 4; ++m)
    #pragma unroll
    for (int nf = 0; nf < 2; ++nf)
      acc[m][nf] = (f32x4){0.f,0.f,0.f,0.f};

  float4 rb[4];
  float4 raf[4][2];     // per m-frag: 8 fp32 of A (two float4)
  {
    const int k0 = 0;
    #pragma unroll
    for (int i = 0; i < 4; ++i)
      rb[i] = *(const float4*)(B + (size_t)(k0 + skk)*2560 + n0 + sc4 + i*32);
    #pragma unroll
    for (int m = 0; m < 4; ++m){
      const float* ap = A + (size_t)(m0 + m*16 + l15)*DIM + k0 + lg*8;
      raf[m][0] = *(const float4*)ap;
      raf[m][1] = *(const float4*)(ap + 4);
    }
  }

  for (int s = 0; s < 64; ++s){
    const int buf = s & 1;
    #pragma unroll
    for (int i = 0; i < 4; ++i)
      *(float4*)&Bs[buf][skk][sc4 + i*32] = rb[i];
    // convert current A frags to hi/lo bf16x8
    bf16x8 ah[4], al[4];
    #pragma unroll
    for (int m = 0; m < 4; ++m){
      float av[8];
      *(float4*)&av[0] = raf[m][0];
      *(float4*)&av[4] = raf[m][1];
      #pragma unroll
      for (int j = 0; j < 8; ++j){
        unsigned short h = f2bf(av[j]);
        float hf = bfbits2f(h);
        unsigned short l = f2bf(av[j] - hf);
        ah[m][j] = (short)h;
        al[m][j] = (short)l;
      }
    }
    __syncthreads();
    if (s + 1 < 64){
      const int k0 = (s+1)*32;
      #pragma unroll
      for (int i = 0; i < 4; ++i)
        rb[i] = *(const float4*)(B + (size_t)(k0 + skk)*2560 + n0 + sc4 + i*32);
      #pragma unroll
      for (int m = 0; m < 4; ++m){
        const float* ap = A + (size_t)(m0 + m*16 + l15)*DIM + k0 + lg*8;
        raf[m][0] = *(const float4*)ap;
        raf[m][1] = *(const float4*)(ap + 4);
      }
    }
    #pragma unroll
    for (int nf = 0; nf < 2; ++nf){
      const int col = wc + nf*16 + l15;
      float bv[8];
      #pragma unroll
      for (int j = 0; j < 8; ++j) bv[j] = Bs[buf][lg*8 + j][col];
      bf16x8 bh, bl;
      #pragma unroll
      for (int j = 0; j < 8; ++j){
        unsigned short h = f2bf(bv[j]);
        float hf = bfbits2f(h);
        unsigned short l = f2bf(bv[j] - hf);
        bh[j] = (short)h;
        bl[j] = (short)l;
      }
      #pragma unroll
      for (int m = 0; m < 4; ++m){
        acc[m][nf] = __builtin_amdgcn_mfma_f32_16x16x32_bf16(ah[m], bh, acc[m][nf], 0, 0, 0);
        acc[m][nf] = __builtin_amdgcn_mfma_f32_16x16x32_bf16(al[m], bh, acc[m][nf], 0, 0, 0);
        acc[m][nf] = __builtin_amdgcn_mfma_f32_16x16x32_bf16(ah[m], bl, acc[m][nf], 0, 0, 0);
      }
    }
  }
  #pragma unroll
  for (int m = 0; m < 4; ++m)
    #pragma unroll
    for (int nf = 0; nf < 2; ++nf){
      const int col = n0 + wc + nf*16 + l15;
      #pragma unroll
      for (int r = 0; r < 4; ++r){
        const int row = m0 + m*16 + lg*4 + r;
        C[(size_t)row*DIM + col] = acc[m][nf][r];
      }
    }
}

// ---------------- RoPE: q fp32 [n][2048], kv fp32 [n][512] -> qr bf16 [n][2048], kr bf16 [n][256] ----
__global__ __launch_bounds__(256) void rope_kernel(const float* __restrict__ q,
    const float* __restrict__ kv, bf16* __restrict__ qr, bf16* __restrict__ kr){
  int n = blockIdx.x, tid = threadIdx.x;
  const float* qrow = q + (size_t)n*DIM;
  bf16* qrrow = qr + (size_t)n*DIM;
  #pragma unroll
  for (int i = 0; i < 4; ++i){
    int p = tid + i*256;
    int hd = p >> 6, ii = p & 63;
    float inv = powf(10000.f, -(float)ii/64.f);
    float ang = (float)n * inv;
    float cs = cosf(ang), sn = sinf(ang);
    float x1 = qrow[hd*DH + 2*ii], x2 = qrow[hd*DH + 2*ii + 1];
    qrrow[hd*DH + 2*ii]     = __float2bfloat16(x1*cs - x2*sn);
    qrrow[hd*DH + 2*ii + 1] = __float2bfloat16(x1*sn + x2*cs);
  }
  if (tid < 128){
    int h = tid >> 6, ii = tid & 63;
    float inv = powf(10000.f, -(float)ii/64.f);
    float ang = (float)n * inv;
    float cs = cosf(ang), sn = sinf(ang);
    const float* kvrow = kv + (size_t)n*512;
    float x1 = kvrow[h*DH + 2*ii], x2 = kvrow[h*DH + 2*ii + 1];
    bf16* krrow = kr + (size_t)n*256;
    krrow[h*DH + 2*ii]     = __float2bfloat16(x1*cs - x2*sn);
    krrow[h*DH + 2*ii + 1] = __float2bfloat16(x1*sn + x2*cs);
  }
}

// ---------------- Build compression-MLP input f [128][CDIM] (k: voff=0, v: voff=256) ----------------
__global__ __launch_bounds__(256) void build_f_kernel(const float* __restrict__ kv, int voff,
    const float* __restrict__ pos, float* __restrict__ f){
  int bw = blockIdx.x;           // h*NWIN + w
  int h = bw >> 6, w = bw & 63;
  int tid = threadIdx.x;
  for (int idx = tid; idx < CMP_BLK*DH; idx += 256){
    int j = idx >> 7, d = idx & 127;
    int t = w*16 + j - 16;       // padded window index
    float kvv = (t >= 0) ? kv[(size_t)t*512 + voff + h*DH + d] : 0.f;
    f[(size_t)bw*CDIM + idx] = kvv + pos[(h*CMP_BLK + j)*DH + d];
  }
}

// ---------------- Assemble ck/cv [KVH][NCMP][DH]; MLP second bias folded here ----------------
__global__ __launch_bounds__(256) void assemble_kernel(const float* __restrict__ ckb,
    const float* __restrict__ cvb, const float* __restrict__ mem_kv,
    const float* __restrict__ bk2, const float* __restrict__ bv2,
    float* __restrict__ ck, float* __restrict__ cv){
  int j = blockIdx.x;            // 0..64
  int tid = threadIdx.x;         // 256 = KVH*DH
  int h = tid >> 7, d = tid & 127;
  float kvx, vvx;
  if (j == 0){
    kvx = mem_kv[(0*KVH + h)*DH + d];
    vvx = mem_kv[(1*KVH + h)*DH + d];
  } else {
    kvx = ckb[((size_t)h*NWIN + (j-1))*DH + d] + bk2[d];
    vvx = cvb[((size_t)h*NWIN + (j-1))*DH + d] + bv2[d];
  }
  ck[((size_t)h*NCMP + j)*DH + d] = kvx;
  cv[((size_t)h*NCMP + j)*DH + d] = vvx;
}

// ---------------- Compressed attention (pre-rope q, fp32) + importance + top-4 selection ----------------
__global__ __launch_bounds__(256) void cmp_attn_kernel(const float* __restrict__ q,
    const float* __restrict__ ck, const float* __restrict__ cv,
    bf16* __restrict__ cmp_o, int* __restrict__ sel){
  int bx = blockIdx.x;
  int h = bx >> 10, n = bx & 1023;
  int tid = threadIdx.x;
  __shared__ float cks[NCMP*129];
  __shared__ float qs[GQ*DH];
  __shared__ float sims[GQ*66];
  __shared__ float red[GQ*32];
  __shared__ float impb[NFINE];
  for (int idx = tid; idx < NCMP*DH; idx += 256){
    int j = idx >> 7, d = idx & 127;
    cks[j*129 + d] = ck[((size_t)h*NCMP + j)*DH + d];
  }
  for (int idx = tid; idx < GQ*DH; idx += 256)
    qs[idx] = q[(size_t)n*DIM + h*(GQ*DH) + idx];
  __syncthreads();
  for (int p = tid; p < GQ*NCMP; p += 256){
    int g = p / NCMP, j = p % NCMP;
    float acc = 0.f;
    const float* qp = &qs[g*DH];
    const float* kp = &cks[j*129];
    #pragma unroll 4
    for (int d = 0; d < DH; ++d) acc += qp[d]*kp[d];
    sims[g*66 + j] = acc * SCALE;
  }
  __syncthreads();
  if (tid < NFINE){
    float s = 0.f;
    for (int g = 0; g < GQ; ++g)
      #pragma unroll
      for (int c = 0; c < 4; ++c)
        s += sims[g*66 + 1 + tid*4 + c];
    impb[tid] = s;
  }
  __syncthreads();
  if (tid == 0){
    int own = n >> 6;
    impb[own] = -1e30f;
    int selbuf[5];
    #pragma unroll
    for (int r = 0; r < 4; ++r){
      float best = -1e38f; int bi = 0;
      for (int f = 0; f < NFINE; ++f)
        if (impb[f] > best){ best = impb[f]; bi = f; }   // strict > : lowest index on ties
      selbuf[r] = bi; impb[bi] = -1e38f;
    }
    selbuf[4] = own;
    for (int r = 0; r < 5; ++r) sel[(size_t)(h*N_TOK + n)*8 + r] = selbuf[r];
  }
  int g = tid >> 5, lane = tid & 31;
  float m = -1e38f;
  for (int j = lane; j < NCMP; j += 32) m = fmaxf(m, sims[g*66 + j]);
  red[g*32 + lane] = m; __syncthreads();
  for (int st = 16; st > 0; st >>= 1){ if (lane < st) red[g*32+lane] = fmaxf(red[g*32+lane], red[g*32+lane+st]); __syncthreads(); }
  float gm = red[g*32]; __syncthreads();
  float ps = 0.f;
  for (int j = lane; j < NCMP; j += 32){ float e = expf(sims[g*66+j] - gm); sims[g*66+j] = e; ps += e; }
  red[g*32+lane] = ps; __syncthreads();
  for (int st = 16; st > 0; st >>= 1){ if (lane < st) red[g*32+lane] += red[g*32+lane+st]; __syncthreads(); }
  float inv = 1.f / red[g*32]; __syncthreads();
  for (int j = lane; j < NCMP; j += 32) sims[g*66+j] *= inv;
  __syncthreads();
  for (int p = tid; p < GQ*DH; p += 256){
    int gg = p >> 7, d = p & 127;
    float acc = 0.f;
    const float* cvp = cv + (size_t)h*NCMP*DH + d;
    for (int j = 0; j < NCMP; ++j) acc += sims[gg*66 + j] * cvp[j*DH];
    cmp_o[(size_t)n*DIM + (h*GQ + gg)*DH + d] = __float2bfloat16(acc);
  }
}

// ---------------- Fine (selected-block) attention — register-blocked outer-product rewrite ----------
// Same math/order as the previous scalar version (bit-identical): QK dots accumulate d ascending,
// PV accumulates t ascending within tile, tiles in order; softmax thread mapping unchanged.
//   * K staged TRANSPOSED kT[d][t] (stride 66): QK thread (qi=tid>>5, tx=tid&31) owns 1x2 outputs;
//     inner d-step: 1 float4 from natural qs (same addr across 32 lanes -> LDS broadcast) +
//     4 float2 kT reads for 8 FMAs (vs 16 scalar reads before).
//   * V staged natural [t][132]: PV thread owns (qi, d-quad); per t: 1 broadcast P scalar +
//     1 float4 V read for 4 FMAs.
//   * kT (128x66) and V (64x132) share one 8448-float buffer (33.8 KB); total LDS ~49 KB.
__global__ __launch_bounds__(256) void fine_attn_kernel(const bf16* __restrict__ qr,
    const bf16* __restrict__ kr, const float* __restrict__ kv,
    const int* __restrict__ sel, bf16* __restrict__ fine_o){
  int bx = blockIdx.x;
  int h = bx >> 10, n = bx & 1023;
  int tid = threadIdx.x;
  __shared__ __align__(16) float kvbuf[8448];   // kT[128][66] (QK) | V[64][132] (PV)
  __shared__ __align__(16) float qs[GQ*DH];     // natural [qi][d]
  __shared__ float sims[GQ*322];
  __shared__ float red[GQ*32];
  const int qi = tid >> 5, tx = tid & 31;

  int sel5[5];
  #pragma unroll
  for (int r = 0; r < 5; ++r){
    int b = sel[(size_t)(h*N_TOK + n)*8 + r];
    sel5[r] = (b < 0) ? 0 : (b > 15 ? 15 : b);
  }
  for (int idx = tid; idx < GQ*DH; idx += 256)
    qs[idx] = b2f(qr[(size_t)n*DIM + h*(GQ*DH) + idx]);

  // ---- QK phase: 5 tiles, K transposed staging, 1x2 micro-tile per thread
  for (int tile = 0; tile < 5; ++tile){
    int blk = sel5[tile];
    __syncthreads();
    for (int c = tid; c < 1024; c += 256){
      int t = c & 63, d0 = (c >> 6) << 3;
      int4 w = *(const int4*)(kr + (size_t)(blk*SEL_BLK + t)*256 + h*DH + d0);
      float* dst = &kvbuf[(size_t)d0*66 + t];
      unsigned int wv[4] = {(unsigned)w.x,(unsigned)w.y,(unsigned)w.z,(unsigned)w.w};
      #pragma unroll
      for (int m = 0; m < 4; ++m){
        dst[(2*m  )*66] = bfbits2f(wv[m] & 0xffffu);
        dst[(2*m+1)*66] = bfbits2f(wv[m] >> 16);
      }
    }
    __syncthreads();
    float acc0 = 0.f, acc1 = 0.f;
    const float* qp = &qs[qi*DH];
    const float* kp = &kvbuf[2*tx];
    #pragma unroll
    for (int d = 0; d < DH; d += 4){
      float4 a = *(const float4*)(qp + d);
      float2 b0 = *(const float2*)(kp + (size_t)(d  )*66);
      float2 b1 = *(const float2*)(kp + (size_t)(d+1)*66);
      float2 b2 = *(const float2*)(kp + (size_t)(d+2)*66);
      float2 b3 = *(const float2*)(kp + (size_t)(d+3)*66);
      acc0 += a.x*b0.x; acc1 += a.x*b0.y;
      acc0 += a.y*b1.x; acc1 += a.y*b1.y;
      acc0 += a.z*b2.x; acc1 += a.z*b2.y;
      acc0 += a.w*b3.x; acc1 += a.w*b3.y;
    }
    *(float2*)&sims[(size_t)qi*322 + tile*SEL_BLK + 2*tx] = make_float2(acc0*SCALE, acc1*SCALE);
  }
  __syncthreads();

  // ---- softmax over 320 (same thread mapping/order as before, stride 322)
  {
    int g = qi, lane = tx;
    float m = -1e38f;
    for (int t = lane; t < T_TOT; t += 32) m = fmaxf(m, sims[g*322 + t]);
    red[g*32+lane] = m; __syncthreads();
    for (int st = 16; st > 0; st >>= 1){ if (lane < st) red[g*32+lane] = fmaxf(red[g*32+lane], red[g*32+lane+st]); __syncthreads(); }
    float gm = red[g*32]; __syncthreads();
    float ps = 0.f;
    for (int t = lane; t < T_TOT; t += 32){ float e = expf(sims[g*322+t] - gm); sims[g*322+t] = e; ps += e; }
    red[g*32+lane] = ps; __syncthreads();
    for (int st = 16; st > 0; st >>= 1){ if (lane < st) red[g*32+lane] += red[g*32+lane+st]; __syncthreads(); }
    float inv = 1.f / red[g*32]; __syncthreads();
    for (int t = lane; t < T_TOT; t += 32) sims[g*322+t] *= inv;
  }

  // ---- PV phase: V natural staging, (qi, d-quad) per thread
  float av[4] = {0.f,0.f,0.f,0.f};
  for (int tile = 0; tile < 5; ++tile){
    int blk = sel5[tile];
    __syncthreads();
    for (int c = tid; c < 2048; c += 256){
      int t = c >> 5, d0 = (c & 31) << 2;
      float4 v = *(const float4*)(kv + (size_t)(blk*SEL_BLK + t)*512 + 256 + h*DH + d0);
      *(float4*)&kvbuf[(size_t)t*132 + d0] = v;
    }
    __syncthreads();
    const float* sp = &sims[(size_t)qi*322 + tile*SEL_BLK];
    const float* vp = &kvbuf[tx << 2];
    #pragma unroll 8
    for (int t = 0; t < SEL_BLK; ++t){
      float p = sp[t];
      float4 v = *(const float4*)(vp + (size_t)t*132);
      av[0] += p*v.x; av[1] += p*v.y; av[2] += p*v.z; av[3] += p*v.w;
    }
  }
  {
    bf16 o[4];
    o[0] = __float2bfloat16(av[0]);
    o[1] = __float2bfloat16(av[1]);
    o[2] = __float2bfloat16(av[2]);
    o[3] = __float2bfloat16(av[3]);
    *(ushort4*)(fine_o + (size_t)n*DIM + (h*GQ + qi)*DH + (tx << 2)) = *(const ushort4*)o;
  }
}

// ---------------- Sliding-window attention, flash-style online softmax --------------------------
__global__ __launch_bounds__(256) void slide_attn_kernel(const bf16* __restrict__ qr,
    const bf16* __restrict__ kr, const float* __restrict__ kv,
    bf16* __restrict__ slide_o){
  int hq = blockIdx.y;          // 16 heads
  int qt = blockIdx.x;          // 32 query tiles of 32
  int h = hq >> 3;
  int n0 = qt * 32;
  int tid = threadIdx.x;
  __shared__ float qT[128*36];   // [d][qi], pad 36
  __shared__ float kvb[128*68];  // K^T [d][t] pad 68 (QK) | V [t][128] (PV)
  __shared__ float stT[64*36];   // [t][qi] exp'd probs, pad 36

  const int ty  = tid >> 5;
  const int tx  = tid & 31;
  const int qi0 = ty << 2;

  for (int c = tid; c < 512; c += 256){
    int qi = c & 31, d0 = (c >> 5) << 3;
    int4 w = *(const int4*)(qr + (size_t)(n0+qi)*DIM + hq*DH + d0);
    float* dst = &qT[(size_t)d0*36 + qi];
    unsigned int wv[4] = {(unsigned)w.x,(unsigned)w.y,(unsigned)w.z,(unsigned)w.w};
    #pragma unroll
    for (int m = 0; m < 4; ++m){
      dst[(2*m  )*36] = bfbits2f(wv[m] & 0xffffu);
      dst[(2*m+1)*36] = bfbits2f(wv[m] >> 16);
    }
  }

  float acc[4][4] = {};
  float mrow[4] = {-1e30f,-1e30f,-1e30f,-1e30f};
  float lrow[4] = {0.f,0.f,0.f,0.f};
  float arow[4];
  const int kstart = n0 - 128;

  for (int tile = 0; tile < 5; ++tile){
    const int kbase = kstart + tile*64;
    __syncthreads();
    for (int c = tid; c < 1024; c += 256){
      int t = c & 63, d0 = (c >> 6) << 3;
      int kg = kbase + t;
      int kgc = min(max(kg, 0), N_TOK-1);
      int4 w = *(const int4*)(kr + (size_t)kgc*256 + h*DH + d0);
      float* dst = &kvb[(size_t)d0*68 + t];
      unsigned int wv[4] = {(unsigned)w.x,(unsigned)w.y,(unsigned)w.z,(unsigned)w.w};
      #pragma unroll
      for (int m = 0; m < 4; ++m){
        dst[(2*m  )*68] = bfbits2f(wv[m] & 0xffffu);
        dst[(2*m+1)*68] = bfbits2f(wv[m] >> 16);
      }
    }
    __syncthreads();
    float c0[8] = {};
    {
      const float* aP = qT + qi0;
      const float* bP = kvb + (tx << 1);
      #pragma unroll 4
      for (int d = 0; d < 128; ++d){
        float4 a = *(const float4*)(aP + d*36);
        float2 b = *(const float2*)(bP + d*68);
        c0[0] += a.x*b.x; c0[1] += a.x*b.y;
        c0[2] += a.y*b.x; c0[3] += a.y*b.y;
        c0[4] += a.z*b.x; c0[5] += a.z*b.y;
        c0[6] += a.w*b.x; c0[7] += a.w*b.y;
      }
    }
    const int kg0 = kbase + (tx << 1);
    #pragma unroll
    for (int i = 0; i < 4; ++i){
      int qg = n0 + qi0 + i;
      int d0 = qg - kg0, d1 = d0 - 1;
      bool v0 = (kg0   >= 0) && (kg0   < N_TOK) && (d0 <= 128) && (d0 >= -128);
      bool v1 = (kg0+1 >= 0) && (kg0+1 < N_TOK) && (d1 <= 128) && (d1 >= -128);
      float s0 = v0 ? c0[i*2  ]*SCALE : -1e30f;
      float s1 = v1 ? c0[i*2+1]*SCALE : -1e30f;
      float mi = fmaxf(s0, s1);
      #pragma unroll
      for (int off = 1; off < 32; off <<= 1) mi = fmaxf(mi, __shfl_xor(mi, off));
      float mold = mrow[i];
      float mnew = fmaxf(fmaxf(mold, mi), -1e20f);
      arow[i] = expf(mold - mnew);
      mrow[i] = mnew;
      float e0 = expf(s0 - mnew);
      float e1 = expf(s1 - mnew);
      float ps = e0 + e1;
      #pragma unroll
      for (int off = 1; off < 32; off <<= 1) ps += __shfl_xor(ps, off);
      lrow[i] = lrow[i]*arow[i] + ps;
      stT[(size_t)(2*tx  )*36 + qi0 + i] = e0;
      stT[(size_t)(2*tx+1)*36 + qi0 + i] = e1;
    }
    __syncthreads();
    for (int c = tid; c < 2048; c += 256){
      int t = c >> 5, d0 = (c & 31) << 2;
      int kg = kbase + t;
      int kgc = min(max(kg, 0), N_TOK-1);
      float4 v = *(const float4*)(kv + (size_t)kgc*512 + 256 + h*DH + d0);
      *(float4*)&kvb[(size_t)t*128 + d0] = v;
    }
    __syncthreads();
    #pragma unroll
    for (int i = 0; i < 4; ++i){
      float ar = arow[i];
      acc[i][0] *= ar; acc[i][1] *= ar; acc[i][2] *= ar; acc[i][3] *= ar;
    }
    {
      const float* pP = stT + qi0;
      const float* vP = kvb + (tx << 2);
      #pragma unroll 4
      for (int t = 0; t < 64; ++t){
        float4 p = *(const float4*)(pP + t*36);
        float4 v = *(const float4*)(vP + t*128);
        acc[0][0] += p.x*v.x; acc[0][1] += p.x*v.y; acc[0][2] += p.x*v.z; acc[0][3] += p.x*v.w;
        acc[1][0] += p.y*v.x; acc[1][1] += p.y*v.y; acc[1][2] += p.y*v.z; acc[1][3] += p.y*v.w;
        acc[2][0] += p.z*v.x; acc[2][1] += p.z*v.y; acc[2][2] += p.z*v.z; acc[2][3] += p.z*v.w;
        acc[3][0] += p.w*v.x; acc[3][1] += p.w*v.y; acc[3][2] += p.w*v.z; acc[3][3] += p.w*v.w;
      }
    }
  }
  #pragma unroll
  for (int i = 0; i < 4; ++i){
    int row = n0 + qi0 + i;
    float inv = 1.f / lrow[i];
    bf16 o[4];
    o[0] = __float2bfloat16(acc[i][0]*inv);
    o[1] = __float2bfloat16(acc[i][1]*inv);
    o[2] = __float2bfloat16(acc[i][2]*inv);
    o[3] = __float2bfloat16(acc[i][3]*inv);
    *(ushort4*)(slide_o + (size_t)row*DIM + hq*DH + (tx << 2)) = *(const ushort4*)o;
  }
}

// ---------------- Gated combine; gate bias+sigmoid folded here -> ocomb bf16 [n][2048] --------------
__global__ __launch_bounds__(256) void combine_kernel(const bf16* __restrict__ cmp_o,
    const bf16* __restrict__ fine_o, const bf16* __restrict__ slide_o,
    const float* __restrict__ graw, const float* __restrict__ bg,
    bf16* __restrict__ ocomb){
  int n = blockIdx.x, tid = threadIdx.x;
  #pragma unroll
  for (int i = 0; i < 8; ++i){
    int c = tid + i*256;
    int hq = c >> 7;
    float g0 = 1.f/(1.f + expf(-(graw[(size_t)n*48 + hq*3 + 0] + bg[hq*3 + 0])));
    float g1 = 1.f/(1.f + expf(-(graw[(size_t)n*48 + hq*3 + 1] + bg[hq*3 + 1])));
    float g2 = 1.f/(1.f + expf(-(graw[(size_t)n*48 + hq*3 + 2] + bg[hq*3 + 2])));
    size_t idx = (size_t)n*DIM + c;
    ocomb[idx] = __float2bfloat16(b2f(cmp_o[idx])*g0 + b2f(fine_o[idx])*g1 + b2f(slide_o[idx])*g2);
  }
}

extern "C" void kernel_launch(void* const* d_in, const int* in_sizes, int n_in,
                              void* d_out, int out_size, void* d_ws, size_t ws_size,
                              hipStream_t stream)
{
  const float* x      = (const float*)d_in[0];
  const float* g_norm = (const float*)d_in[1];
  const float* W_qkv  = (const float*)d_in[2];
  const float* k_pos  = (const float*)d_in[3];
  const float* v_pos  = (const float*)d_in[4];
  const float* mem_kv = (const float*)d_in[5];
  const float* Wk1    = (const float*)d_in[6];
  const float* bk1    = (const float*)d_in[7];
  const float* Wk2    = (const float*)d_in[8];
  const float* bk2    = (const float*)d_in[9];
  const float* Wv1    = (const float*)d_in[10];
  const float* bv1    = (const float*)d_in[11];
  const float* Wv2    = (const float*)d_in[12];
  const float* bv2    = (const float*)d_in[13];
  const float* Wg     = (const float*)d_in[14];
  const float* bg     = (const float*)d_in[15];
  const float* W_out  = (const float*)d_in[16];
  float* out = (float*)d_out;
  (void)ws_size; (void)in_sizes; (void)n_in; (void)out_size;

  // ---- Workspace layout (bytes), total ~23.6 MB, aggressive region reuse ----
  char* base = (char*)d_ws;
  float* q     = (float*)(base + 0);                 // 8 MB [n][2048] fp32, live -> cmp_attn
  float* xn    = (float*)(base + 8388608);           // 8 MB fp32, live -> kv GEMM
  bf16*  qr    = (bf16*) (base + 8388608);           // 4 MB (over xn, after xn dead)
  bf16*  kr    = (bf16*) (base + 12582912);          // 0.5 MB
  bf16*  ocomb = (bf16*) (base + 8388608);           // 4 MB (over qr, after slide)
  float* kv    = (float*)(base + 16777216);          // 2 MB [n][512] fp32
  float* fbuf  = (float*)(base + 18874368);          // 2 MB fk / fv
  float* hbuf  = (float*)(base + 20971520);          // 2 MB hk / hv (raw, bias folded downstream)
  bf16*  cmp_o = (bf16*) (base + 18874368);          // 4 MB (over fbuf+hbuf, after MLPs)
  float* ckb   = (float*)(base + 23068672);          // 64 KB (raw)
  float* cvb   = (float*)(base + 23134208);          // 64 KB (raw)
  float* ck    = (float*)(base + 23199744);          // 65 KB
  float* cv    = (float*)(base + 23266304);          // 65 KB
  float* gates = (float*)(base + 23332864);          // 192 KB (raw, sigmoid folded in combine)
  int*   sel   = (int*)  (base + 23529472);          // 64 KB   (end: 23,595,008 B)
  bf16*  fine_o  = (bf16*)(base + 0);                // 4 MB (over q, after cmp_attn)
  bf16*  slide_o = (bf16*)(base + 4194304);          // 4 MB (over q upper half)

  // Zero split-K accumulation targets (stream-ordered; graph-capture legal)
  hipMemsetAsync(kv,    0, (size_t)N_TOK*512*4,  stream);
  hipMemsetAsync(gates, 0, (size_t)N_TOK*48*4,   stream);
  hipMemsetAsync(ckb,   0, (size_t)KVH*NWIN*DH*4, stream);
  hipMemsetAsync(cvb,   0, (size_t)KVH*NWIN*DH*4, stream);

  rmsnorm_kernel<<<N_TOK, 256, 0, stream>>>(x, g_norm, xn);
  // gates_raw = xn @ Wg            [1024 x 48],  small -> old 64x64 kernel
  gemm_splitk_kernel<<<dim3(1, 16, 8), 256, 0, stream>>>(xn, 0, nullptr, Wg, 48, gates, N_TOK, 48, DIM, 256);
  // q = xn @ W_qkv[:, 0:2048] via 3-term hi/lo MFMA (direct stores, ~1e-5-class residual)
  gemm_mfma_q_kernel<<<dim3(16, 16), 256, 0, stream>>>(xn, W_qkv, q);
  // kv = xn @ W_qkv[:, 2048:2560]  [1024 x 512], 64x128 dbuf, kchunk=256 (exact fp32 path)
  gemm64_db_kernel<<<dim3(4, 16, 8), 256, 0, stream>>>(xn, W_qkv + 2048, 2560, kv, N_TOK, 512, DIM, 256);
  // qr, kr (bf16) — xn now dead
  rope_kernel<<<N_TOK, 256, 0, stream>>>(q, kv, qr, kr);
  // compression MLPs (fp32, selection-critical via ck). relu(.+bk1) folded into MLP2 A-load; bk2 into assemble.
  build_f_kernel<<<KVH*NWIN, 256, 0, stream>>>(kv, 0, k_pos, fbuf);
  hipMemsetAsync(hbuf, 0, (size_t)KVH*NWIN*CDIM*4, stream);
  gemm64_db_kernel<<<dim3(32, 2, 8), 256, 0, stream>>>(fbuf, Wk1, CDIM, hbuf, KVH*NWIN, CDIM, CDIM, 512);
  gemm_splitk_kernel<<<dim3(2, 2, 32),  256, 0, stream>>>(hbuf, 0, bk1,     Wk2, DH,   ckb,  KVH*NWIN, DH,   CDIM, 128);
  build_f_kernel<<<KVH*NWIN, 256, 0, stream>>>(kv, 256, v_pos, fbuf);
  hipMemsetAsync(hbuf, 0, (size_t)KVH*NWIN*CDIM*4, stream);
  gemm64_db_kernel<<<dim3(32, 2, 8), 256, 0, stream>>>(fbuf, Wv1, CDIM, hbuf, KVH*NWIN, CDIM, CDIM, 512);
  gemm_splitk_kernel<<<dim3(2, 2, 32),  256, 0, stream>>>(hbuf, 0, bv1,     Wv2, DH,   cvb,  KVH*NWIN, DH,   CDIM, 128);
  assemble_kernel<<<NCMP, 256, 0, stream>>>(ckb, cvb, mem_kv, bk2, bv2, ck, cv);
  // compressed attention + selection (fbuf/hbuf dead -> cmp_o)
  cmp_attn_kernel<<<KVH*N_TOK, 256, 0, stream>>>(q, ck, cv, cmp_o, sel);
  // fine attention (q dead -> fine_o over q region)
  fine_attn_kernel<<<KVH*N_TOK, 256, 0, stream>>>(qr, kr, kv, sel, fine_o);
  // sliding attention (-> slide_o over q upper half)
  slide_attn_kernel<<<dim3(32, 16), 256, 0, stream>>>(qr, kr, kv, slide_o);
  // combine (qr dead -> ocomb over qr); sigmoid(graw+bg) folded here
  combine_kernel<<<N_TOK, 256, 0, stream>>>(cmp_o, fine_o, slide_o, gates, bg, ocomb);
  // out = ocomb @ W_out via bf16 MFMA with hi/lo-split B (near-fp32 exact, no atomics, direct stores)
  gemm_mfma_out_kernel<<<dim3(16, 16), 256, 0, stream>>>(ocomb, W_out, out);
}